// Round 1
// baseline (616.992 us; speedup 1.0000x reference)
//
#include <hip/hip_runtime.h>
#include <hip/hip_fp16.h>

#define F16 _Float16
typedef F16 f16x8 __attribute__((ext_vector_type(8)));
typedef F16 f16x4 __attribute__((ext_vector_type(4)));
typedef float f32x4 __attribute__((ext_vector_type(4)));

// ---------------- f32 -> f16 convert (vectorized) ----------------
__global__ void cvt_f32_f16(const float* __restrict__ src, F16* __restrict__ dst, int n) {
    int idx = blockIdx.x * blockDim.x + threadIdx.x;
    int stride = gridDim.x * blockDim.x;
    for (int i = idx * 4; i < n; i += stride * 4) {
        float4 v = *reinterpret_cast<const float4*>(src + i);
        f16x4 o;
        o[0] = (F16)v.x; o[1] = (F16)v.y; o[2] = (F16)v.z; o[3] = (F16)v.w;
        *reinterpret_cast<f16x4*>(dst + i) = o;
    }
}

// ---------------- async global->LDS 16B ----------------
__device__ __forceinline__ void gl_lds16(const F16* g, F16* l) {
    __builtin_amdgcn_global_load_lds(
        (const __attribute__((address_space(1))) void*)g,
        (__attribute__((address_space(3))) void*)l, 16, 0, 0);
}

// ---------------- NT GEMM: C[M][N] = A[M][K] * Bw[N][K]^T ----------------
// 128x128 tile, BK=32, 256 threads (4 waves, each a 64x64 quadrant of 4x4 16x16 frags).
// LDS staged in FRAGMENT ORDER: chunk n = rb*64 + lane holds
//   A[brow + rb*16 + (lane&15)][k0 + (lane>>4)*8 .. +7]  (16 bytes)
// so both global_load_lds (linear dest) and ds_read_b128 (lane*16) are conflict-free.
// EPI==0: QKV epilogue (scatter to q/k/v ws, q pre-scaled, v transposed [B,H,D,S])
// EPI==1: f32 out + bias
template <int EPI>
__global__ __launch_bounds__(256, 2) void gemm_nt(
    const F16* __restrict__ A, const F16* __restrict__ Bw, const float* __restrict__ bias,
    F16* __restrict__ q_ws, F16* __restrict__ k_ws, F16* __restrict__ v_ws,
    float* __restrict__ fout, int M, int N, int K)
{
    __shared__ __align__(16) F16 lds[2][2][4096];  // [dbuf][A/B][8 rb][64 lane][8 f16]
    const int tid = threadIdx.x;
    const int w = tid >> 6, l = tid & 63;
    const int lr = l & 15, lg = l >> 4;
    const int nbm = M >> 7;
    const int mb = blockIdx.x % nbm;
    const int nb = blockIdx.x / nbm;
    const long brow = (long)mb * 128;
    const long bcol = (long)nb * 128;
    const int wr = w >> 1, wc = w & 1;

    f32x4 acc[4][4];
#pragma unroll
    for (int i = 0; i < 4; ++i)
#pragma unroll
        for (int j = 0; j < 4; ++j) acc[i][j] = f32x4{0.f, 0.f, 0.f, 0.f};

    const F16* Abase = A + brow * K;
    const F16* Bbase = Bw + bcol * K;

    auto stage = [&](int buf, int kt) {
        const int k0 = kt << 5;
#pragma unroll
        for (int i = 0; i < 2; ++i) {
            const int rb = (i * 256 + tid) >> 6;
            const F16* sa = Abase + (long)(rb * 16 + lr) * K + k0 + lg * 8;
            gl_lds16(sa, &lds[buf][0][(i * 256 + w * 64) * 8]);
        }
#pragma unroll
        for (int i = 0; i < 2; ++i) {
            const int rb = (i * 256 + tid) >> 6;
            const F16* sb = Bbase + (long)(rb * 16 + lr) * K + k0 + lg * 8;
            gl_lds16(sb, &lds[buf][1][(i * 256 + w * 64) * 8]);
        }
    };

    const int nk = K >> 5;
    stage(0, 0);
    __syncthreads();
    int cur = 0;
    for (int kt = 0; kt < nk; ++kt) {
        if (kt + 1 < nk) stage(cur ^ 1, kt + 1);
        f16x8 af[4], bf[4];
#pragma unroll
        for (int mi = 0; mi < 4; ++mi)
            af[mi] = *reinterpret_cast<const f16x8*>(&lds[cur][0][((wr * 4 + mi) * 64 + l) * 8]);
#pragma unroll
        for (int ni = 0; ni < 4; ++ni)
            bf[ni] = *reinterpret_cast<const f16x8*>(&lds[cur][1][((wc * 4 + ni) * 64 + l) * 8]);
#pragma unroll
        for (int mi = 0; mi < 4; ++mi)
#pragma unroll
            for (int ni = 0; ni < 4; ++ni)
                acc[mi][ni] = __builtin_amdgcn_mfma_f32_16x16x32_f16(af[mi], bf[ni], acc[mi][ni], 0, 0, 0);
        __syncthreads();
        cur ^= 1;
    }

    // Epilogue. C/D layout: row = (lane>>4)*4 + reg, col = lane&15 [verified m89].
    const int r0 = wr * 64 + lg * 4;
    const int c0 = wc * 64 + lr;
    if constexpr (EPI == 0) {
        const int part = (int)(bcol >> 11);          // 0=q 1=k 2=v (block is 128-col aligned)
        const int hh = ((int)bcol >> 7) & 15;        // head (constant per block)
        const int bI = (int)(brow >> 10);            // batch (constant per block)
        const int s_base = ((int)brow & 1023) + r0;
#pragma unroll
        for (int mi = 0; mi < 4; ++mi) {
#pragma unroll
            for (int ni = 0; ni < 4; ++ni) {
                const int d = c0 + ni * 16;          // 0..127 within head
                const float bv = bias[bcol + d];
                if (part == 2) {
                    f16x4 pv;
#pragma unroll
                    for (int r = 0; r < 4; ++r) pv[r] = (F16)(acc[mi][ni][r] + bv);
                    const int s0 = s_base + mi * 16;
                    F16* dst = v_ws + ((long)((bI * 16 + hh) * 128 + d)) * 1024 + s0;
                    *reinterpret_cast<f16x4*>(dst) = pv;  // 4 consecutive s -> 8B store
                } else {
                    F16* base = (part == 0) ? q_ws : k_ws;
                    const float scl = (part == 0) ? 0.08838834764831845f : 1.0f;  // 1/sqrt(128)
#pragma unroll
                    for (int r = 0; r < 4; ++r) {
                        const int s = s_base + mi * 16 + r;
                        base[((long)((bI * 16 + hh) * 1024 + s)) * 128 + d] =
                            (F16)((acc[mi][ni][r] + bv) * scl);
                    }
                }
            }
        }
    } else {
#pragma unroll
        for (int mi = 0; mi < 4; ++mi)
#pragma unroll
            for (int ni = 0; ni < 4; ++ni) {
                const long row = brow + r0 + mi * 16;
                const long col = bcol + c0 + ni * 16;
                const float bv = bias[col];
#pragma unroll
                for (int r = 0; r < 4; ++r)
                    fout[(row + r) * N + col] = acc[mi][ni][r] + bv;
            }
    }
}

// ---------------- flash attention ----------------
// grid: 1024 blocks = 64 (b,h) * 16 q-tiles; 4 waves x 16 q-rows each.
// Q pre-scaled by 1/sqrt(D). K: [B,H,S,D]; V: [B,H,D,S] (transposed).
// K/V read straight from global (L2-resident: 512KB per (b,h)).
__global__ __launch_bounds__(256, 3) void attn_kernel(
    const F16* __restrict__ q_ws, const F16* __restrict__ k_ws,
    const F16* __restrict__ v_ws, F16* __restrict__ ctx)
{
    __shared__ __align__(16) F16 p_lds[4][512];  // per-wave 16x32 P, read-optimal order
    const int tid = threadIdx.x;
    const int w = tid >> 6, l = tid & 63;
    const int lr = l & 15, lg = l >> 4;
    const int bh = blockIdx.x >> 4;
    const int qt = blockIdx.x & 15;
    const int b = bh >> 4, h = bh & 15;
    const int q0 = qt * 64 + w * 16;

    // Q fragments: A-layout row=lane&15, k=(lane>>4)*8+j
    const F16* qbase = q_ws + ((long)bh * 1024 + q0 + lr) * 128 + lg * 8;
    f16x8 qf[4];
#pragma unroll
    for (int ks = 0; ks < 4; ++ks) qf[ks] = *reinterpret_cast<const f16x8*>(qbase + ks * 32);

    const F16* kbase = k_ws + ((long)bh * 1024 + lr) * 128 + lg * 8;
    const F16* vbase = v_ws + ((long)bh * 128 + lr) * 1024 + lg * 8;

    float mrun[4], lsum[4];
#pragma unroll
    for (int r = 0; r < 4; ++r) { mrun[r] = -1e30f; lsum[r] = 0.f; }
    f32x4 acc[8];
#pragma unroll
    for (int nf = 0; nf < 8; ++nf) acc[nf] = f32x4{0.f, 0.f, 0.f, 0.f};

    for (int kv = 0; kv < 1024; kv += 32) {
        // scores: S[16 q][32 kv] as two 16-col frags
        f32x4 sc[2];
        sc[0] = f32x4{0.f, 0.f, 0.f, 0.f};
        sc[1] = f32x4{0.f, 0.f, 0.f, 0.f};
#pragma unroll
        for (int cf = 0; cf < 2; ++cf) {
            const F16* kp = kbase + (long)(kv + cf * 16) * 128;
#pragma unroll
            for (int ks = 0; ks < 4; ++ks) {
                f16x8 kf = *reinterpret_cast<const f16x8*>(kp + ks * 32);
                sc[cf] = __builtin_amdgcn_mfma_f32_16x16x32_f16(qf[ks], kf, sc[cf], 0, 0, 0);
            }
        }
        // online softmax (rows live on the 16 lanes sharing lg; reduce over lane&15)
        float t[4];
#pragma unroll
        for (int r = 0; r < 4; ++r) t[r] = fmaxf(sc[0][r], sc[1][r]);
#pragma unroll
        for (int msk = 1; msk < 16; msk <<= 1)
#pragma unroll
            for (int r = 0; r < 4; ++r) t[r] = fmaxf(t[r], __shfl_xor(t[r], msk));
        float al[4], p0[4], p1[4], rs[4];
#pragma unroll
        for (int r = 0; r < 4; ++r) {
            float mn = fmaxf(mrun[r], t[r]);
            al[r] = __expf(mrun[r] - mn);
            mrun[r] = mn;
            p0[r] = __expf(sc[0][r] - mn);
            p1[r] = __expf(sc[1][r] - mn);
            rs[r] = p0[r] + p1[r];
        }
#pragma unroll
        for (int msk = 1; msk < 16; msk <<= 1)
#pragma unroll
            for (int r = 0; r < 4; ++r) rs[r] += __shfl_xor(rs[r], msk);
#pragma unroll
        for (int r = 0; r < 4; ++r) lsum[r] = lsum[r] * al[r] + rs[r];
#pragma unroll
        for (int nf = 0; nf < 8; ++nf)
#pragma unroll
            for (int r = 0; r < 4; ++r) acc[nf][r] *= al[r];
        // P (C-layout) -> LDS in A-fragment-read-optimal order:
        // ushort index = (c>>3)*128 + row*8 + (c&7); reader lane reads [l*8 .. l*8+7]
#pragma unroll
        for (int cf = 0; cf < 2; ++cf)
#pragma unroll
            for (int r = 0; r < 4; ++r) {
                const int rr = lg * 4 + r;
                const int c = cf * 16 + lr;
                p_lds[w][(c >> 3) * 128 + rr * 8 + (c & 7)] = (F16)(cf ? p1[r] : p0[r]);
            }
        f16x8 pf = *reinterpret_cast<const f16x8*>(&p_lds[w][l * 8]);
        // O += P * V ; B-frag: V^T[kv + lg*8 + j][d = nf*16 + lr] via transposed v_ws
#pragma unroll
        for (int nf = 0; nf < 8; ++nf) {
            f16x8 vf = *reinterpret_cast<const f16x8*>(vbase + (long)(nf * 16) * 1024 + kv);
            acc[nf] = __builtin_amdgcn_mfma_f32_16x16x32_f16(pf, vf, acc[nf], 0, 0, 0);
        }
    }
    // epilogue: ctx[b][s][h*128 + d] bf16(f16) normalized
    float inv[4];
#pragma unroll
    for (int r = 0; r < 4; ++r) inv[r] = 1.f / lsum[r];
#pragma unroll
    for (int nf = 0; nf < 8; ++nf)
#pragma unroll
        for (int r = 0; r < 4; ++r) {
            const int s = q0 + lg * 4 + r;
            const int e = h * 128 + nf * 16 + lr;
            ctx[((long)(b * 1024 + s)) * 2048 + e] = (F16)(acc[nf][r] * inv[r]);
        }
}

// ---------------- launch ----------------
extern "C" void kernel_launch(void* const* d_in, const int* in_sizes, int n_in,
                              void* d_out, int out_size, void* d_ws, size_t ws_size,
                              hipStream_t stream) {
    const float* query = (const float*)d_in[0];
    const float* w_in  = (const float*)d_in[1];
    const float* b_in  = (const float*)d_in[2];
    const float* w_out = (const float*)d_in[3];
    const float* b_out = (const float*)d_in[4];
    float* out = (float*)d_out;

    char* ws = (char*)d_ws;
    size_t off = 0;
    auto carve = [&](size_t bytes) -> void* {
        void* p = ws + off;
        off += (bytes + 255) & ~(size_t)255;
        return p;
    };
    F16* xq  = (F16*)carve(8388608ULL * 2);   // query f16 [4096][2048]
    F16* wih = (F16*)carve(12582912ULL * 2);  // in_proj_weight f16 [6144][2048]
    F16* woh = (F16*)carve(4194304ULL * 2);   // out_proj_weight f16 [2048][2048]
    F16* qws = (F16*)carve(8388608ULL * 2);   // Q [B,H,S,D] pre-scaled
    F16* kws = (F16*)carve(8388608ULL * 2);   // K [B,H,S,D]
    F16* vws = (F16*)carve(8388608ULL * 2);   // V [B,H,D,S] (transposed)
    F16* ctx = (F16*)carve(8388608ULL * 2);   // ctx [B,S,E]

    cvt_f32_f16<<<1024, 256, 0, stream>>>(query, xq, 8388608);
    cvt_f32_f16<<<1024, 256, 0, stream>>>(w_in, wih, 12582912);
    cvt_f32_f16<<<512, 256, 0, stream>>>(w_out, woh, 4194304);

    // QKV: M=4096 tokens, N=6144, K=2048
    gemm_nt<0><<<32 * 48, 256, 0, stream>>>(xq, wih, b_in, qws, kws, vws, nullptr, 4096, 6144, 2048);
    // attention
    attn_kernel<<<1024, 256, 0, stream>>>(qws, kws, vws, ctx);
    // out proj: M=4096, N=2048, K=2048
    gemm_nt<1><<<32 * 16, 256, 0, stream>>>(ctx, woh, b_out, nullptr, nullptr, nullptr, out, 4096, 2048, 2048);
}

// Round 3
// 455.555 us; speedup vs baseline: 1.3544x; 1.3544x over previous
//
#include <hip/hip_runtime.h>
#include <hip/hip_fp16.h>

#define F16 _Float16
typedef F16 f16x8 __attribute__((ext_vector_type(8)));
typedef F16 f16x4 __attribute__((ext_vector_type(4)));
typedef float f32x4 __attribute__((ext_vector_type(4)));

// ---------------- f32 -> f16 convert (vectorized) ----------------
__global__ void cvt_f32_f16(const float* __restrict__ src, F16* __restrict__ dst, int n) {
    int idx = blockIdx.x * blockDim.x + threadIdx.x;
    int stride = gridDim.x * blockDim.x;
    for (int i = idx * 4; i < n; i += stride * 4) {
        float4 v = *reinterpret_cast<const float4*>(src + i);
        f16x4 o;
        o[0] = (F16)v.x; o[1] = (F16)v.y; o[2] = (F16)v.z; o[3] = (F16)v.w;
        *reinterpret_cast<f16x4*>(dst + i) = o;
    }
}

// ---------------- async global->LDS 16B ----------------
__device__ __forceinline__ void gl_lds16(const F16* g, F16* l) {
    __builtin_amdgcn_global_load_lds(
        (const __attribute__((address_space(1))) void*)g,
        (__attribute__((address_space(3))) void*)l, 16, 0, 0);
}

// ---------------- NT GEMM: C[M][N] = A[M][K] * Bw[N][K]^T ----------------
// (unchanged from round 1 — 128x128 tile, BK=32, fragment-order LDS)
template <int EPI>
__global__ __launch_bounds__(256, 2) void gemm_nt(
    const F16* __restrict__ A, const F16* __restrict__ Bw, const float* __restrict__ bias,
    F16* __restrict__ q_ws, F16* __restrict__ k_ws, F16* __restrict__ v_ws,
    float* __restrict__ fout, int M, int N, int K)
{
    __shared__ __align__(16) F16 lds[2][2][4096];
    const int tid = threadIdx.x;
    const int w = tid >> 6, l = tid & 63;
    const int lr = l & 15, lg = l >> 4;
    const int nbm = M >> 7;
    const int mb = blockIdx.x % nbm;
    const int nb = blockIdx.x / nbm;
    const long brow = (long)mb * 128;
    const long bcol = (long)nb * 128;
    const int wr = w >> 1, wc = w & 1;

    f32x4 acc[4][4];
#pragma unroll
    for (int i = 0; i < 4; ++i)
#pragma unroll
        for (int j = 0; j < 4; ++j) acc[i][j] = f32x4{0.f, 0.f, 0.f, 0.f};

    const F16* Abase = A + brow * K;
    const F16* Bbase = Bw + bcol * K;

    auto stage = [&](int buf, int kt) {
        const int k0 = kt << 5;
#pragma unroll
        for (int i = 0; i < 2; ++i) {
            const int rb = (i * 256 + tid) >> 6;
            const F16* sa = Abase + (long)(rb * 16 + lr) * K + k0 + lg * 8;
            gl_lds16(sa, &lds[buf][0][(i * 256 + w * 64) * 8]);
        }
#pragma unroll
        for (int i = 0; i < 2; ++i) {
            const int rb = (i * 256 + tid) >> 6;
            const F16* sb = Bbase + (long)(rb * 16 + lr) * K + k0 + lg * 8;
            gl_lds16(sb, &lds[buf][1][(i * 256 + w * 64) * 8]);
        }
    };

    const int nk = K >> 5;
    stage(0, 0);
    __syncthreads();
    int cur = 0;
    for (int kt = 0; kt < nk; ++kt) {
        if (kt + 1 < nk) stage(cur ^ 1, kt + 1);
        f16x8 af[4], bf[4];
#pragma unroll
        for (int mi = 0; mi < 4; ++mi)
            af[mi] = *reinterpret_cast<const f16x8*>(&lds[cur][0][((wr * 4 + mi) * 64 + l) * 8]);
#pragma unroll
        for (int ni = 0; ni < 4; ++ni)
            bf[ni] = *reinterpret_cast<const f16x8*>(&lds[cur][1][((wc * 4 + ni) * 64 + l) * 8]);
#pragma unroll
        for (int mi = 0; mi < 4; ++mi)
#pragma unroll
            for (int ni = 0; ni < 4; ++ni)
                acc[mi][ni] = __builtin_amdgcn_mfma_f32_16x16x32_f16(af[mi], bf[ni], acc[mi][ni], 0, 0, 0);
        __syncthreads();
        cur ^= 1;
    }

    const int r0 = wr * 64 + lg * 4;
    const int c0 = wc * 64 + lr;
    if constexpr (EPI == 0) {
        const int part = (int)(bcol >> 11);
        const int hh = ((int)bcol >> 7) & 15;
        const int bI = (int)(brow >> 10);
        const int s_base = ((int)brow & 1023) + r0;
#pragma unroll
        for (int mi = 0; mi < 4; ++mi) {
#pragma unroll
            for (int ni = 0; ni < 4; ++ni) {
                const int d = c0 + ni * 16;
                const float bv = bias[bcol + d];
                if (part == 2) {
                    f16x4 pv;
#pragma unroll
                    for (int r = 0; r < 4; ++r) pv[r] = (F16)(acc[mi][ni][r] + bv);
                    const int s0 = s_base + mi * 16;
                    F16* dst = v_ws + ((long)((bI * 16 + hh) * 128 + d)) * 1024 + s0;
                    *reinterpret_cast<f16x4*>(dst) = pv;
                } else {
                    F16* base = (part == 0) ? q_ws : k_ws;
                    const float scl = (part == 0) ? 0.08838834764831845f : 1.0f;
#pragma unroll
                    for (int r = 0; r < 4; ++r) {
                        const int s = s_base + mi * 16 + r;
                        base[((long)((bI * 16 + hh) * 1024 + s)) * 128 + d] =
                            (F16)((acc[mi][ni][r] + bv) * scl);
                    }
                }
            }
        }
    } else {
#pragma unroll
        for (int mi = 0; mi < 4; ++mi)
#pragma unroll
            for (int ni = 0; ni < 4; ++ni) {
                const long row = brow + r0 + mi * 16;
                const long col = bcol + c0 + ni * 16;
                const float bv = bias[col];
#pragma unroll
                for (int r = 0; r < 4; ++r)
                    fout[(row + r) * N + col] = acc[mi][ni][r] + bv;
            }
    }
}

// ---------------- flash attention v2 ----------------
// 512 blocks = 64 (b,h) * 8 q-tiles of 128 rows; 4 waves x 32 q-rows.
// K,V tiles (KVBLK=64) LDS-staged cooperatively (global_load_lds, dbuf),
// XOR-swizzled (byte ^= (row&7)<<4) via pre-swizzled global source.
// XCD swizzle: 64 works per XCD -> 8 (b,h) per XCD (KV footprint 4MB = L2).
__global__ __launch_bounds__(256, 2) void attn_kernel(
    const F16* __restrict__ q_ws, const F16* __restrict__ k_ws,
    const F16* __restrict__ v_ws, F16* __restrict__ ctx)
{
    __shared__ __align__(16) F16 kt[2][64 * 128];   // 32KB
    __shared__ __align__(16) F16 vt[2][128 * 64];   // 32KB
    __shared__ __align__(16) F16 p_lds[4][2048];    // 16KB (per-wave 32x64 P)
    const int tid = threadIdx.x;
    const int w = tid >> 6, l = tid & 63;
    const int lr = l & 15, lg = l >> 4;
    // XCD-aware swizzle (512 % 8 == 0, bijective)
    const int work = (blockIdx.x & 7) * 64 + (blockIdx.x >> 3);
    const int bh = work >> 3, qt = work & 7;
    const int b = bh >> 4, h = bh & 15;
    const int q0 = qt * 128 + w * 32;

    const F16* kbh = k_ws + (long)bh * 1024 * 128;
    const F16* vbh = v_ws + (long)bh * 128 * 1024;

    // Q fragments: A-layout row=lane&15, k=(lane>>4)*8+j  (Q pre-scaled by 1/sqrt(D))
    f16x8 qf[2][4];
#pragma unroll
    for (int mi = 0; mi < 2; ++mi)
#pragma unroll
        for (int ks = 0; ks < 4; ++ks)
            qf[mi][ks] = *reinterpret_cast<const f16x8*>(
                q_ws + ((long)bh * 1024 + q0 + mi * 16 + lr) * 128 + ks * 32 + lg * 8);

    auto stage = [&](int buf, int kv0) {
        // K tile: [64][128] f16 = 1024 chunks of 16B; rows 256B; contiguous in global.
#pragma unroll
        for (int t = 0; t < 4; ++t) {
            const int chunk = t * 256 + tid;
            const int row = chunk >> 4;
            const int colb = (chunk & 15) << 4;
            const int gcol = colb ^ ((row & 7) << 4);  // pre-swizzled source
            gl_lds16(kbh + (long)(kv0 + row) * 128 + (gcol >> 1),
                     &kt[buf][(t * 256 + w * 64) * 8]);
        }
        // V tile: [128][64] f16 (v_ws is [B,H,D,S]); rows 128B.
#pragma unroll
        for (int t = 0; t < 4; ++t) {
            const int chunk = t * 256 + tid;
            const int d = chunk >> 3;
            const int colb = (chunk & 7) << 4;
            const int gcol = colb ^ ((d & 7) << 4);
            gl_lds16(vbh + (long)d * 1024 + kv0 + (gcol >> 1),
                     &vt[buf][(t * 256 + w * 64) * 8]);
        }
    };

    float mrun[2][4], lsum[2][4];
#pragma unroll
    for (int mi = 0; mi < 2; ++mi)
#pragma unroll
        for (int r = 0; r < 4; ++r) { mrun[mi][r] = -1e30f; lsum[mi][r] = 0.f; }
    f32x4 acc[2][8];
#pragma unroll
    for (int mi = 0; mi < 2; ++mi)
#pragma unroll
        for (int nf = 0; nf < 8; ++nf) acc[mi][nf] = f32x4{0.f, 0.f, 0.f, 0.f};

    stage(0, 0);
    __syncthreads();
    int cur = 0;
    for (int it = 0; it < 16; ++it) {
        if (it + 1 < 16) stage(cur ^ 1, (it + 1) * 64);

        // ---- QK^T: S[32 q][64 kv] as 2 mi x 4 cf frags ----
        f32x4 sc[2][4];
#pragma unroll
        for (int mi = 0; mi < 2; ++mi)
#pragma unroll
            for (int cf = 0; cf < 4; ++cf) sc[mi][cf] = f32x4{0.f, 0.f, 0.f, 0.f};
#pragma unroll
        for (int cf = 0; cf < 4; ++cf) {
#pragma unroll
            for (int ks = 0; ks < 4; ++ks) {
                const int row = cf * 16 + lr;
                const int eff = (ks * 64 + lg * 16) ^ ((row & 7) << 4);
                f16x8 kf = *reinterpret_cast<const f16x8*>(&kt[cur][row * 128 + (eff >> 1)]);
#pragma unroll
                for (int mi = 0; mi < 2; ++mi)
                    sc[mi][cf] = __builtin_amdgcn_mfma_f32_16x16x32_f16(qf[mi][ks], kf, sc[mi][cf], 0, 0, 0);
            }
        }

        // ---- online softmax (rows on 16-lane groups; reduce over lane&15) ----
#pragma unroll
        for (int mi = 0; mi < 2; ++mi) {
            float t4[4];
#pragma unroll
            for (int r = 0; r < 4; ++r)
                t4[r] = fmaxf(fmaxf(sc[mi][0][r], sc[mi][1][r]), fmaxf(sc[mi][2][r], sc[mi][3][r]));
#pragma unroll
            for (int msk = 1; msk < 16; msk <<= 1)
#pragma unroll
                for (int r = 0; r < 4; ++r) t4[r] = fmaxf(t4[r], __shfl_xor(t4[r], msk));
            float al[4], rs[4], p[4][4];
#pragma unroll
            for (int r = 0; r < 4; ++r) {
                const float mn = fmaxf(mrun[mi][r], t4[r]);
                al[r] = __expf(mrun[mi][r] - mn);
                mrun[mi][r] = mn;
#pragma unroll
                for (int cf = 0; cf < 4; ++cf) p[cf][r] = __expf(sc[mi][cf][r] - mn);
                rs[r] = (p[0][r] + p[1][r]) + (p[2][r] + p[3][r]);
            }
#pragma unroll
            for (int msk = 1; msk < 16; msk <<= 1)
#pragma unroll
                for (int r = 0; r < 4; ++r) rs[r] += __shfl_xor(rs[r], msk);
#pragma unroll
            for (int r = 0; r < 4; ++r) lsum[mi][r] = lsum[mi][r] * al[r] + rs[r];
#pragma unroll
            for (int nf = 0; nf < 8; ++nf)
#pragma unroll
                for (int r = 0; r < 4; ++r) acc[mi][nf][r] *= al[r];
            // P (C-layout) -> per-wave LDS in A-frag-read order
#pragma unroll
            for (int cf = 0; cf < 4; ++cf)
#pragma unroll
                for (int r = 0; r < 4; ++r) {
                    const int chunk = (mi * 2 + (cf >> 1)) * 64 + (lg * 4 + r) + ((cf & 1) * 2 + (lr >> 3)) * 16;
                    p_lds[w][chunk * 8 + (lr & 7)] = (F16)p[cf][r];
                }
        }

        // ---- PV: O += P * V ----
        f16x8 pf[2][2];
#pragma unroll
        for (int mi = 0; mi < 2; ++mi)
#pragma unroll
            for (int half = 0; half < 2; ++half)
                pf[mi][half] = *reinterpret_cast<const f16x8*>(&p_lds[w][((mi * 2 + half) * 64 + l) * 8]);
#pragma unroll
        for (int nf = 0; nf < 8; ++nf) {
#pragma unroll
            for (int half = 0; half < 2; ++half) {
                const int d = nf * 16 + lr;
                const int eff = (half * 64 + lg * 16) ^ ((d & 7) << 4);
                f16x8 vf = *reinterpret_cast<const f16x8*>(&vt[cur][d * 64 + (eff >> 1)]);
#pragma unroll
                for (int mi = 0; mi < 2; ++mi)
                    acc[mi][nf] = __builtin_amdgcn_mfma_f32_16x16x32_f16(pf[mi][half], vf, acc[mi][nf], 0, 0, 0);
            }
        }
        __syncthreads();
        cur ^= 1;
    }

    // ---- epilogue: ctx[b][s][h*128+d], normalized ----
#pragma unroll
    for (int mi = 0; mi < 2; ++mi) {
        float inv[4];
#pragma unroll
        for (int r = 0; r < 4; ++r) inv[r] = 1.f / lsum[mi][r];
#pragma unroll
        for (int nf = 0; nf < 8; ++nf)
#pragma unroll
            for (int r = 0; r < 4; ++r) {
                const int s = q0 + mi * 16 + lg * 4 + r;
                const int e = h * 128 + nf * 16 + lr;
                ctx[((long)(b * 1024 + s)) * 2048 + e] = (F16)(acc[mi][nf][r] * inv[r]);
            }
    }
}

// ---------------- launch ----------------
extern "C" void kernel_launch(void* const* d_in, const int* in_sizes, int n_in,
                              void* d_out, int out_size, void* d_ws, size_t ws_size,
                              hipStream_t stream) {
    const float* query = (const float*)d_in[0];
    const float* w_in  = (const float*)d_in[1];
    const float* b_in  = (const float*)d_in[2];
    const float* w_out = (const float*)d_in[3];
    const float* b_out = (const float*)d_in[4];
    float* out = (float*)d_out;

    char* ws = (char*)d_ws;
    size_t off = 0;
    auto carve = [&](size_t bytes) -> void* {
        void* p = ws + off;
        off += (bytes + 255) & ~(size_t)255;
        return p;
    };
    F16* xq  = (F16*)carve(8388608ULL * 2);   // query f16 [4096][2048]
    F16* wih = (F16*)carve(12582912ULL * 2);  // in_proj_weight f16 [6144][2048]
    F16* woh = (F16*)carve(4194304ULL * 2);   // out_proj_weight f16 [2048][2048]
    F16* qws = (F16*)carve(8388608ULL * 2);   // Q [B,H,S,D] pre-scaled
    F16* kws = (F16*)carve(8388608ULL * 2);   // K [B,H,S,D]
    F16* vws = (F16*)carve(8388608ULL * 2);   // V [B,H,D,S] (transposed)
    F16* ctx = (F16*)carve(8388608ULL * 2);   // ctx [B,S,E]

    cvt_f32_f16<<<1024, 256, 0, stream>>>(query, xq, 8388608);
    cvt_f32_f16<<<1024, 256, 0, stream>>>(w_in, wih, 12582912);
    cvt_f32_f16<<<512, 256, 0, stream>>>(w_out, woh, 4194304);

    gemm_nt<0><<<32 * 48, 256, 0, stream>>>(xq, wih, b_in, qws, kws, vws, nullptr, 4096, 6144, 2048);
    attn_kernel<<<512, 256, 0, stream>>>(qws, kws, vws, ctx);
    gemm_nt<1><<<32 * 16, 256, 0, stream>>>(ctx, woh, b_out, nullptr, nullptr, nullptr, out, 4096, 2048, 2048);
}

// Round 4
// 418.483 us; speedup vs baseline: 1.4744x; 1.0886x over previous
//
#include <hip/hip_runtime.h>
#include <hip/hip_fp16.h>

#define F16 _Float16
typedef F16 f16x8 __attribute__((ext_vector_type(8)));
typedef F16 f16x4 __attribute__((ext_vector_type(4)));
typedef float f32x4 __attribute__((ext_vector_type(4)));

// ---------------- f32 -> f16 convert (vectorized) ----------------
__global__ void cvt_f32_f16(const float* __restrict__ src, F16* __restrict__ dst, int n) {
    int idx = blockIdx.x * blockDim.x + threadIdx.x;
    int stride = gridDim.x * blockDim.x;
    for (int i = idx * 4; i < n; i += stride * 4) {
        float4 v = *reinterpret_cast<const float4*>(src + i);
        f16x4 o;
        o[0] = (F16)v.x; o[1] = (F16)v.y; o[2] = (F16)v.z; o[3] = (F16)v.w;
        *reinterpret_cast<f16x4*>(dst + i) = o;
    }
}

// ---------------- async global->LDS 16B ----------------
__device__ __forceinline__ void gl_lds16(const F16* g, F16* l) {
    __builtin_amdgcn_global_load_lds(
        (const __attribute__((address_space(1))) void*)g,
        (__attribute__((address_space(3))) void*)l, 16, 0, 0);
}

// ---------------- 256x256 8-phase NT GEMM (T3+T4+T5) ----------------
// C[M][N] = A[M][K] * Bw[N][K]^T. BK=64, 512 threads = 8 waves (2M x 4N).
// Wave output 128x64 = 8 M-frags x 4 N-frags (16x16x32 MFMA).
// LDS [2 buf][4 regions: A-rows0-127, A-rows128-255, B-cols0-127, B-cols128-255]
// in FRAGMENT ORDER: chunk c = (frag*2+ksub)*64+lane holds row frag*16+(lane&15),
// k = ksub*32+(lane>>4)*8 (16B) -> linear gl_lds dest + conflict-free ds_read_b128.
// Per K-tile: 4 phases; phase p computes M-frags {2p,2p+1} x all N x ksub0/1 (16 MFMA).
// Staging stream S(t) -> buf[t&1]: B0@t-2.p1, B1@t-2.p2, A-heads@t-2.p3, A-tails@t-1.p0
// (each target region is dead: read completes >=1 phase before overwrite issue).
// vmcnt(6) once per K-tile (p3) => S(t+1) fully landed entering tile t+1. Never 0 mid-loop.
template <int EPI>
__global__ __launch_bounds__(512, 2) void gemm8(
    const F16* __restrict__ A, const F16* __restrict__ Bw, const float* __restrict__ bias,
    F16* __restrict__ q_ws, F16* __restrict__ k_ws, F16* __restrict__ v_ws,
    float* __restrict__ fout, int M, int N, int K)
{
    __shared__ __align__(16) F16 lds[2][4][8192];  // 128 KiB
    const int tid = threadIdx.x;
    const int w = tid >> 6, l = tid & 63;
    const int lr = l & 15, lg = l >> 4;
    const int wm = w >> 2, wn = w & 3;

    // XCD-chunked swizzle (grid % 8 == 0): each XCD gets a contiguous work range
    // covering 2 mb values x all nb -> 2MB of A panels L2-resident per XCD.
    const int nbn = N >> 8;
    const int cpx = (int)gridDim.x >> 3;
    const int work = ((int)blockIdx.x & 7) * cpx + ((int)blockIdx.x >> 3);
    const int nb = work % nbn, mb = work / nbn;
    const long brow = (long)mb * 256, bcol = (long)nb * 256;

    const F16* rb0 = A + brow * K;                 // A rows 0-127 of tile
    const F16* rb1 = rb0 + 128 * (long)K;          // A rows 128-255
    const F16* rb2 = Bw + bcol * K;                // B cols 0-127
    const F16* rb3 = rb2 + 128 * (long)K;          // B cols 128-255

    // staging decomposition (issue S in {0,1} covers chunks [S*512, S*512+512))
    const int sr0 = ((tid >> 7) << 4) + (tid & 15);                 // row for S=0
    const int skk = (((tid >> 6) & 1) << 5) + (((tid >> 4) & 3) << 3);  // k within tile
    const int wb8 = (w << 6) * 8;                                   // wave-uniform LDS base (elems)

#define GISSUE(BUF, R, S, KT, RB) \
    gl_lds16(RB + (long)(sr0 + S * 64) * K + (KT) * 64 + skk, \
             &lds[BUF][R][S * 4096 + wb8])

    const int NK = K >> 6;

    f32x4 acc[8][4];
#pragma unroll
    for (int f = 0; f < 8; ++f)
#pragma unroll
        for (int nf = 0; nf < 4; ++nf) acc[f][nf] = f32x4{0.f, 0.f, 0.f, 0.f};

    // ---- prologue: S(0) full (8 issues), S(1) B + A-heads (6 issues) ----
    GISSUE(0, 0, 0, 0, rb0); GISSUE(0, 0, 1, 0, rb0);
    GISSUE(0, 1, 0, 0, rb1); GISSUE(0, 1, 1, 0, rb1);
    GISSUE(0, 2, 0, 0, rb2); GISSUE(0, 2, 1, 0, rb2);
    GISSUE(0, 3, 0, 0, rb3); GISSUE(0, 3, 1, 0, rb3);
    if (NK > 1) {
        GISSUE(1, 2, 0, 1, rb2); GISSUE(1, 2, 1, 1, rb2);
        GISSUE(1, 3, 0, 1, rb3); GISSUE(1, 3, 1, 1, rb3);
        GISSUE(1, 0, 0, 1, rb0); GISSUE(1, 1, 0, 1, rb1);
        asm volatile("s_waitcnt vmcnt(6)" ::: "memory");  // S(0) landed
    } else {
        asm volatile("s_waitcnt vmcnt(0)" ::: "memory");
    }
    __builtin_amdgcn_s_barrier();

    for (int kt = 0; kt < NK; ++kt) {
        const int cur = kt & 1, nxt = cur ^ 1;
        const F16* Areg = &lds[cur][wm][0];
        const F16* Breg = &lds[cur][2 + (wn >> 1)][0];
        // B-frags for whole K-tile (8 x ds_read_b128), held in regs across phases
        f16x8 b[4][2];
#pragma unroll
        for (int nf = 0; nf < 4; ++nf)
#pragma unroll
            for (int ks = 0; ks < 2; ++ks)
                b[nf][ks] = *reinterpret_cast<const f16x8*>(
                    Breg + ((((wn & 1) * 4 + nf) * 2 + ks) * 64 + l) * 8);
#pragma unroll
        for (int p = 0; p < 4; ++p) {
            // A-frags for this phase (4 x ds_read_b128)
            f16x8 a[2][2];
#pragma unroll
            for (int mf = 0; mf < 2; ++mf)
#pragma unroll
                for (int ks = 0; ks < 2; ++ks)
                    a[mf][ks] = *reinterpret_cast<const f16x8*>(
                        Areg + (((2 * p + mf) * 2 + ks) * 64 + l) * 8);
            // staging (2 gl_lds/phase into dead regions)
            if (p == 0) {
                if (kt + 1 < NK) { GISSUE(nxt, 0, 1, kt + 1, rb0); GISSUE(nxt, 1, 1, kt + 1, rb1); }
            } else if (p == 1) {
                if (kt + 2 < NK) { GISSUE(cur, 2, 0, kt + 2, rb2); GISSUE(cur, 2, 1, kt + 2, rb2); }
            } else if (p == 2) {
                if (kt + 2 < NK) { GISSUE(cur, 3, 0, kt + 2, rb3); GISSUE(cur, 3, 1, kt + 2, rb3); }
            } else {
                if (kt + 2 < NK) { GISSUE(cur, 0, 0, kt + 2, rb0); GISSUE(cur, 1, 0, kt + 2, rb1); }
            }
            __builtin_amdgcn_sched_barrier(0);
            __builtin_amdgcn_s_barrier();
            asm volatile("s_waitcnt lgkmcnt(0)" ::: "memory");
            __builtin_amdgcn_sched_barrier(0);
            __builtin_amdgcn_s_setprio(1);
#pragma unroll
            for (int mf = 0; mf < 2; ++mf)
#pragma unroll
                for (int nf = 0; nf < 4; ++nf)
#pragma unroll
                    for (int ks = 0; ks < 2; ++ks)
                        acc[2 * p + mf][nf] = __builtin_amdgcn_mfma_f32_16x16x32_f16(
                            a[mf][ks], b[nf][ks], acc[2 * p + mf][nf], 0, 0, 0);
            __builtin_amdgcn_s_setprio(0);
            __builtin_amdgcn_sched_barrier(0);
            if (p == 3) {
                if (kt + 2 < NK) asm volatile("s_waitcnt vmcnt(6)" ::: "memory");
                else             asm volatile("s_waitcnt vmcnt(0)" ::: "memory");
            }
            __builtin_amdgcn_s_barrier();
        }
    }
#undef GISSUE

    // ---- epilogue (C/D layout: row=lg*4+reg, col=lr) ----
    const int col0 = (int)bcol + wn * 64;
    const int row0 = (int)brow + wm * 128;
    if constexpr (EPI == 0) {
        const int part = (int)(bcol >> 11);        // 0=q 1=k 2=v (block never crosses)
        const int bI = row0 >> 10;
        const int sb = row0 & 1023;
        const float scl = (part == 0) ? 0.08838834764831845f : 1.0f;  // 1/sqrt(128)
#pragma unroll
        for (int nf = 0; nf < 4; ++nf) {
            const int gcol = col0 + nf * 16 + lr;
            const float bv = bias[gcol];
            const int d = gcol & 127;
            const int hh = (gcol >> 7) & 15;
            if (part == 2) {
                F16* dst0 = v_ws + ((long)((bI * 16 + hh) * 128 + d)) * 1024;
#pragma unroll
                for (int f = 0; f < 8; ++f) {
                    f16x4 pv;
#pragma unroll
                    for (int r = 0; r < 4; ++r) pv[r] = (F16)(acc[f][nf][r] + bv);
                    *reinterpret_cast<f16x4*>(dst0 + sb + f * 16 + lg * 4) = pv;
                }
            } else {
                F16* dst0 = ((part == 0) ? q_ws : k_ws) + ((long)(bI * 16 + hh) * 1024) * 128 + d;
#pragma unroll
                for (int f = 0; f < 8; ++f)
#pragma unroll
                    for (int r = 0; r < 4; ++r)
                        dst0[(long)(sb + f * 16 + lg * 4 + r) * 128] =
                            (F16)((acc[f][nf][r] + bv) * scl);
            }
        }
    } else {
#pragma unroll
        for (int nf = 0; nf < 4; ++nf) {
            const int gcol = col0 + nf * 16 + lr;
            const float bv = bias[gcol];
#pragma unroll
            for (int f = 0; f < 8; ++f)
#pragma unroll
                for (int r = 0; r < 4; ++r)
                    fout[(long)(row0 + f * 16 + lg * 4 + r) * N + gcol] = acc[f][nf][r] + bv;
        }
    }
}

// ---------------- flash attention (unchanged from round 3) ----------------
__global__ __launch_bounds__(256, 2) void attn_kernel(
    const F16* __restrict__ q_ws, const F16* __restrict__ k_ws,
    const F16* __restrict__ v_ws, F16* __restrict__ ctx)
{
    __shared__ __align__(16) F16 kt[2][64 * 128];
    __shared__ __align__(16) F16 vt[2][128 * 64];
    __shared__ __align__(16) F16 p_lds[4][2048];
    const int tid = threadIdx.x;
    const int w = tid >> 6, l = tid & 63;
    const int lr = l & 15, lg = l >> 4;
    const int work = (blockIdx.x & 7) * 64 + (blockIdx.x >> 3);
    const int bh = work >> 3, qt = work & 7;
    const int b = bh >> 4, h = bh & 15;
    const int q0 = qt * 128 + w * 32;

    const F16* kbh = k_ws + (long)bh * 1024 * 128;
    const F16* vbh = v_ws + (long)bh * 128 * 1024;

    f16x8 qf[2][4];
#pragma unroll
    for (int mi = 0; mi < 2; ++mi)
#pragma unroll
        for (int ks = 0; ks < 4; ++ks)
            qf[mi][ks] = *reinterpret_cast<const f16x8*>(
                q_ws + ((long)bh * 1024 + q0 + mi * 16 + lr) * 128 + ks * 32 + lg * 8);

    auto stage = [&](int buf, int kv0) {
#pragma unroll
        for (int t = 0; t < 4; ++t) {
            const int chunk = t * 256 + tid;
            const int row = chunk >> 4;
            const int colb = (chunk & 15) << 4;
            const int gcol = colb ^ ((row & 7) << 4);
            gl_lds16(kbh + (long)(kv0 + row) * 128 + (gcol >> 1),
                     &kt[buf][(t * 256 + w * 64) * 8]);
        }
#pragma unroll
        for (int t = 0; t < 4; ++t) {
            const int chunk = t * 256 + tid;
            const int d = chunk >> 3;
            const int colb = (chunk & 7) << 4;
            const int gcol = colb ^ ((d & 7) << 4);
            gl_lds16(vbh + (long)d * 1024 + kv0 + (gcol >> 1),
                     &vt[buf][(t * 256 + w * 64) * 8]);
        }
    };

    float mrun[2][4], lsum[2][4];
#pragma unroll
    for (int mi = 0; mi < 2; ++mi)
#pragma unroll
        for (int r = 0; r < 4; ++r) { mrun[mi][r] = -1e30f; lsum[mi][r] = 0.f; }
    f32x4 acc[2][8];
#pragma unroll
    for (int mi = 0; mi < 2; ++mi)
#pragma unroll
        for (int nf = 0; nf < 8; ++nf) acc[mi][nf] = f32x4{0.f, 0.f, 0.f, 0.f};

    stage(0, 0);
    __syncthreads();
    int cur = 0;
    for (int it = 0; it < 16; ++it) {
        if (it + 1 < 16) stage(cur ^ 1, (it + 1) * 64);

        f32x4 sc[2][4];
#pragma unroll
        for (int mi = 0; mi < 2; ++mi)
#pragma unroll
            for (int cf = 0; cf < 4; ++cf) sc[mi][cf] = f32x4{0.f, 0.f, 0.f, 0.f};
#pragma unroll
        for (int cf = 0; cf < 4; ++cf) {
#pragma unroll
            for (int ks = 0; ks < 4; ++ks) {
                const int row = cf * 16 + lr;
                const int eff = (ks * 64 + lg * 16) ^ ((row & 7) << 4);
                f16x8 kf = *reinterpret_cast<const f16x8*>(&kt[cur][row * 128 + (eff >> 1)]);
#pragma unroll
                for (int mi = 0; mi < 2; ++mi)
                    sc[mi][cf] = __builtin_amdgcn_mfma_f32_16x16x32_f16(qf[mi][ks], kf, sc[mi][cf], 0, 0, 0);
            }
        }

#pragma unroll
        for (int mi = 0; mi < 2; ++mi) {
            float t4[4];
#pragma unroll
            for (int r = 0; r < 4; ++r)
                t4[r] = fmaxf(fmaxf(sc[mi][0][r], sc[mi][1][r]), fmaxf(sc[mi][2][r], sc[mi][3][r]));
#pragma unroll
            for (int msk = 1; msk < 16; msk <<= 1)
#pragma unroll
                for (int r = 0; r < 4; ++r) t4[r] = fmaxf(t4[r], __shfl_xor(t4[r], msk));
            float al[4], rs[4], p[4][4];
#pragma unroll
            for (int r = 0; r < 4; ++r) {
                const float mn = fmaxf(mrun[mi][r], t4[r]);
                al[r] = __expf(mrun[mi][r] - mn);
                mrun[mi][r] = mn;
#pragma unroll
                for (int cf = 0; cf < 4; ++cf) p[cf][r] = __expf(sc[mi][cf][r] - mn);
                rs[r] = (p[0][r] + p[1][r]) + (p[2][r] + p[3][r]);
            }
#pragma unroll
            for (int msk = 1; msk < 16; msk <<= 1)
#pragma unroll
                for (int r = 0; r < 4; ++r) rs[r] += __shfl_xor(rs[r], msk);
#pragma unroll
            for (int r = 0; r < 4; ++r) lsum[mi][r] = lsum[mi][r] * al[r] + rs[r];
#pragma unroll
            for (int nf = 0; nf < 8; ++nf)
#pragma unroll
                for (int r = 0; r < 4; ++r) acc[mi][nf][r] *= al[r];
#pragma unroll
            for (int cf = 0; cf < 4; ++cf)
#pragma unroll
                for (int r = 0; r < 4; ++r) {
                    const int chunk = (mi * 2 + (cf >> 1)) * 64 + (lg * 4 + r) + ((cf & 1) * 2 + (lr >> 3)) * 16;
                    p_lds[w][chunk * 8 + (lr & 7)] = (F16)p[cf][r];
                }
        }

        f16x8 pf[2][2];
#pragma unroll
        for (int mi = 0; mi < 2; ++mi)
#pragma unroll
            for (int half = 0; half < 2; ++half)
                pf[mi][half] = *reinterpret_cast<const f16x8*>(&p_lds[w][((mi * 2 + half) * 64 + l) * 8]);
#pragma unroll
        for (int nf = 0; nf < 8; ++nf) {
#pragma unroll
            for (int half = 0; half < 2; ++half) {
                const int d = nf * 16 + lr;
                const int eff = (half * 64 + lg * 16) ^ ((d & 7) << 4);
                f16x8 vf = *reinterpret_cast<const f16x8*>(&vt[cur][d * 64 + (eff >> 1)]);
#pragma unroll
                for (int mi = 0; mi < 2; ++mi)
                    acc[mi][nf] = __builtin_amdgcn_mfma_f32_16x16x32_f16(pf[mi][half], vf, acc[mi][nf], 0, 0, 0);
            }
        }
        __syncthreads();
        cur ^= 1;
    }

#pragma unroll
    for (int mi = 0; mi < 2; ++mi) {
        float inv[4];
#pragma unroll
        for (int r = 0; r < 4; ++r) inv[r] = 1.f / lsum[mi][r];
#pragma unroll
        for (int nf = 0; nf < 8; ++nf)
#pragma unroll
            for (int r = 0; r < 4; ++r) {
                const int s = q0 + mi * 16 + lg * 4 + r;
                const int e = h * 128 + nf * 16 + lr;
                ctx[((long)(b * 1024 + s)) * 2048 + e] = (F16)(acc[mi][nf][r] * inv[r]);
            }
    }
}

// ---------------- launch ----------------
extern "C" void kernel_launch(void* const* d_in, const int* in_sizes, int n_in,
                              void* d_out, int out_size, void* d_ws, size_t ws_size,
                              hipStream_t stream) {
    const float* query = (const float*)d_in[0];
    const float* w_in  = (const float*)d_in[1];
    const float* b_in  = (const float*)d_in[2];
    const float* w_out = (const float*)d_in[3];
    const float* b_out = (const float*)d_in[4];
    float* out = (float*)d_out;

    char* ws = (char*)d_ws;
    size_t off = 0;
    auto carve = [&](size_t bytes) -> void* {
        void* p = ws + off;
        off += (bytes + 255) & ~(size_t)255;
        return p;
    };
    F16* xq  = (F16*)carve(8388608ULL * 2);   // query f16 [4096][2048]
    F16* wih = (F16*)carve(12582912ULL * 2);  // in_proj_weight f16 [6144][2048]
    F16* woh = (F16*)carve(4194304ULL * 2);   // out_proj_weight f16 [2048][2048]
    F16* qws = (F16*)carve(8388608ULL * 2);   // Q [B,H,S,D] pre-scaled
    F16* kws = (F16*)carve(8388608ULL * 2);   // K [B,H,S,D]
    F16* vws = (F16*)carve(8388608ULL * 2);   // V [B,H,D,S] (transposed)
    F16* ctx = (F16*)carve(8388608ULL * 2);   // ctx [B,S,E]

    cvt_f32_f16<<<1024, 256, 0, stream>>>(query, xq, 8388608);
    cvt_f32_f16<<<1024, 256, 0, stream>>>(w_in, wih, 12582912);
    cvt_f32_f16<<<512, 256, 0, stream>>>(w_out, woh, 4194304);

    // QKV: M=4096, N=6144, K=2048 -> 16x24 = 384 blocks of 512 threads
    gemm8<0><<<384, 512, 0, stream>>>(xq, wih, b_in, qws, kws, vws, nullptr, 4096, 6144, 2048);
    attn_kernel<<<512, 256, 0, stream>>>(qws, kws, vws, ctx);
    // out proj: M=4096, N=2048, K=2048 -> 16x8 = 128 blocks
    gemm8<1><<<128, 512, 0, stream>>>(ctx, woh, b_out, nullptr, nullptr, nullptr, out, 4096, 2048, 2048);
}

// Round 7
// 402.770 us; speedup vs baseline: 1.5319x; 1.0390x over previous
//
#include <hip/hip_runtime.h>
#include <hip/hip_fp16.h>

#define F16 _Float16
typedef F16 f16x8 __attribute__((ext_vector_type(8)));
typedef F16 f16x4 __attribute__((ext_vector_type(4)));
typedef float f32x4 __attribute__((ext_vector_type(4)));

// ---------------- f32 -> f16 convert (vectorized) ----------------
__global__ void cvt_f32_f16(const float* __restrict__ src, F16* __restrict__ dst, int n) {
    int idx = blockIdx.x * blockDim.x + threadIdx.x;
    int stride = gridDim.x * blockDim.x;
    for (int i = idx * 4; i < n; i += stride * 4) {
        float4 v = *reinterpret_cast<const float4*>(src + i);
        f16x4 o;
        o[0] = (F16)v.x; o[1] = (F16)v.y; o[2] = (F16)v.z; o[3] = (F16)v.w;
        *reinterpret_cast<f16x4*>(dst + i) = o;
    }
}

// ---------------- async global->LDS 16B ----------------
__device__ __forceinline__ void gl_lds16(const F16* g, F16* l) {
    __builtin_amdgcn_global_load_lds(
        (const __attribute__((address_space(1))) void*)g,
        (__attribute__((address_space(3))) void*)l, 16, 0, 0);
}

// ---------------- QKV GEMM: 256x256 8-phase (T3+T4+T5) ----------------
// grid MUST be 384 = 16mb x 24nb. XCD 2-D chunk: 8mb x 6nb per XCD
// (working set 8x1MB A + 6x1MB B = 14MB/XCD vs 27MB for 2x24).
__global__ __launch_bounds__(512, 2) void gemm8qkv(
    const F16* __restrict__ A, const F16* __restrict__ Bw, const float* __restrict__ bias,
    F16* __restrict__ q_ws, F16* __restrict__ k_ws, F16* __restrict__ v_ws,
    int M, int N, int K)
{
    __shared__ __align__(16) F16 lds[2][4][8192];  // 128 KiB
    const int tid = threadIdx.x;
    const int w = tid >> 6, l = tid & 63;
    const int lr = l & 15, lg = l >> 4;
    const int wm = w >> 2, wn = w & 3;

    const int xcd = (int)blockIdx.x & 7, s5 = (int)blockIdx.x >> 3;  // s5 0..47
    const int mb = (xcd & 1) * 8 + s5 / 6;
    const int nb = (xcd >> 1) * 6 + s5 % 6;
    const long brow = (long)mb * 256, bcol = (long)nb * 256;

    const F16* rb0 = A + brow * K;
    const F16* rb1 = rb0 + 128 * (long)K;
    const F16* rb2 = Bw + bcol * K;
    const F16* rb3 = rb2 + 128 * (long)K;

    const int sr0 = ((tid >> 7) << 4) + (tid & 15);
    const int skk = (((tid >> 6) & 1) << 5) + (((tid >> 4) & 3) << 3);
    const int wb8 = (w << 6) * 8;

#define GISSUE(BUF, R, S, KT, RB) \
    gl_lds16(RB + (long)(sr0 + S * 64) * K + (KT) * 64 + skk, \
             &lds[BUF][R][S * 4096 + wb8])

    const int NK = K >> 6;

    f32x4 acc[8][4];
#pragma unroll
    for (int f = 0; f < 8; ++f)
#pragma unroll
        for (int nf = 0; nf < 4; ++nf) acc[f][nf] = f32x4{0.f, 0.f, 0.f, 0.f};

    GISSUE(0, 0, 0, 0, rb0); GISSUE(0, 0, 1, 0, rb0);
    GISSUE(0, 1, 0, 0, rb1); GISSUE(0, 1, 1, 0, rb1);
    GISSUE(0, 2, 0, 0, rb2); GISSUE(0, 2, 1, 0, rb2);
    GISSUE(0, 3, 0, 0, rb3); GISSUE(0, 3, 1, 0, rb3);
    if (NK > 1) {
        GISSUE(1, 2, 0, 1, rb2); GISSUE(1, 2, 1, 1, rb2);
        GISSUE(1, 3, 0, 1, rb3); GISSUE(1, 3, 1, 1, rb3);
        GISSUE(1, 0, 0, 1, rb0); GISSUE(1, 1, 0, 1, rb1);
        asm volatile("s_waitcnt vmcnt(6)" ::: "memory");
    } else {
        asm volatile("s_waitcnt vmcnt(0)" ::: "memory");
    }
    __builtin_amdgcn_s_barrier();

    for (int kt = 0; kt < NK; ++kt) {
        const int cur = kt & 1, nxt = cur ^ 1;
        const F16* Areg = &lds[cur][wm][0];
        const F16* Breg = &lds[cur][2 + (wn >> 1)][0];
        f16x8 b[4][2];
#pragma unroll
        for (int nf = 0; nf < 4; ++nf)
#pragma unroll
            for (int ks = 0; ks < 2; ++ks)
                b[nf][ks] = *reinterpret_cast<const f16x8*>(
                    Breg + ((((wn & 1) * 4 + nf) * 2 + ks) * 64 + l) * 8);
#pragma unroll
        for (int p = 0; p < 4; ++p) {
            f16x8 a[2][2];
#pragma unroll
            for (int mf = 0; mf < 2; ++mf)
#pragma unroll
                for (int ks = 0; ks < 2; ++ks)
                    a[mf][ks] = *reinterpret_cast<const f16x8*>(
                        Areg + (((2 * p + mf) * 2 + ks) * 64 + l) * 8);
            if (p == 0) {
                if (kt + 1 < NK) { GISSUE(nxt, 0, 1, kt + 1, rb0); GISSUE(nxt, 1, 1, kt + 1, rb1); }
            } else if (p == 1) {
                if (kt + 2 < NK) { GISSUE(cur, 2, 0, kt + 2, rb2); GISSUE(cur, 2, 1, kt + 2, rb2); }
            } else if (p == 2) {
                if (kt + 2 < NK) { GISSUE(cur, 3, 0, kt + 2, rb3); GISSUE(cur, 3, 1, kt + 2, rb3); }
            } else {
                if (kt + 2 < NK) { GISSUE(cur, 0, 0, kt + 2, rb0); GISSUE(cur, 1, 0, kt + 2, rb1); }
            }
            __builtin_amdgcn_sched_barrier(0);
            __builtin_amdgcn_s_barrier();
            asm volatile("s_waitcnt lgkmcnt(0)" ::: "memory");
            __builtin_amdgcn_sched_barrier(0);
            __builtin_amdgcn_s_setprio(1);
#pragma unroll
            for (int mf = 0; mf < 2; ++mf)
#pragma unroll
                for (int nf = 0; nf < 4; ++nf)
#pragma unroll
                    for (int ks = 0; ks < 2; ++ks)
                        acc[2 * p + mf][nf] = __builtin_amdgcn_mfma_f32_16x16x32_f16(
                            a[mf][ks], b[nf][ks], acc[2 * p + mf][nf], 0, 0, 0);
            __builtin_amdgcn_s_setprio(0);
            __builtin_amdgcn_sched_barrier(0);
            if (p == 3) {
                if (kt + 2 < NK) asm volatile("s_waitcnt vmcnt(6)" ::: "memory");
                else             asm volatile("s_waitcnt vmcnt(0)" ::: "memory");
            }
            __builtin_amdgcn_s_barrier();
        }
    }
#undef GISSUE

    // epilogue: scatter q/k/v (C/D layout: row=lg*4+reg, col=lr)
    const int col0 = (int)bcol + wn * 64;
    const int row0 = (int)brow + wm * 128;
    const int part = (int)(bcol >> 11);
    const int bI = row0 >> 10;
    const int sb = row0 & 1023;
    const float scl = (part == 0) ? 0.08838834764831845f : 1.0f;  // 1/sqrt(128)
#pragma unroll
    for (int nf = 0; nf < 4; ++nf) {
        const int gcol = col0 + nf * 16 + lr;
        const float bv = bias[gcol];
        const int d = gcol & 127;
        const int hh = (gcol >> 7) & 15;
        if (part == 2) {
            F16* dst0 = v_ws + ((long)((bI * 16 + hh) * 128 + d)) * 1024;
#pragma unroll
            for (int f = 0; f < 8; ++f) {
                f16x4 pv;
#pragma unroll
                for (int r = 0; r < 4; ++r) pv[r] = (F16)(acc[f][nf][r] + bv);
                *reinterpret_cast<f16x4*>(dst0 + sb + f * 16 + lg * 4) = pv;
            }
        } else {
            F16* dst0 = ((part == 0) ? q_ws : k_ws) + ((long)(bI * 16 + hh) * 1024) * 128 + d;
#pragma unroll
            for (int f = 0; f < 8; ++f)
#pragma unroll
                for (int r = 0; r < 4; ++r)
                    dst0[(long)(sb + f * 16 + lg * 4 + r) * 128] =
                        (F16)((acc[f][nf][r] + bv) * scl);
        }
    }
}

// ---------------- out-proj GEMM: 128x256 tile, grid 256 = 1 block/CU ----------------
// 8 waves (2M x 4N), wave tile 64x64 = 4x4 frags. BK=64, 2 phases x 16 MFMA.
// LDS [2buf][A(128x64) | B0(128x64) | B1(128x64)] = 96KB, fragment order.
// Staging: A of S(t+1) at p0 (2 issues), B of S(t+2) at p1 (4 issues); vmcnt(4)/tile.
__global__ __launch_bounds__(512, 2) void gemm8out(
    const F16* __restrict__ A, const F16* __restrict__ Bw, const float* __restrict__ bias,
    float* __restrict__ fout, int M, int N, int K)
{
    __shared__ __align__(16) F16 lds[2][3][8192];  // 96 KiB
    const int tid = threadIdx.x;
    const int w = tid >> 6, l = tid & 63;
    const int lr = l & 15, lg = l >> 4;
    const int wm = w >> 2, wn = w & 3;

    // grid MUST be 256 = 32mb x 8nb; XCD chunk 8mb x 4nb
    const int xcd = (int)blockIdx.x & 7, s5 = (int)blockIdx.x >> 3;  // s5 0..31
    const int mb = (xcd & 3) * 8 + (s5 >> 2);
    const int nb = (xcd >> 2) * 4 + (s5 & 3);
    const long brow = (long)mb * 128, bcol = (long)nb * 256;

    const F16* rbA = A + brow * K;
    const F16* rb2 = Bw + bcol * K;
    const F16* rb3 = rb2 + 128 * (long)K;

    const int sr0 = ((tid >> 7) << 4) + (tid & 15);
    const int skk = (((tid >> 6) & 1) << 5) + (((tid >> 4) & 3) << 3);
    const int wb8 = (w << 6) * 8;

#define GISSUE(BUF, R, S, KT, RB) \
    gl_lds16(RB + (long)(sr0 + S * 64) * K + (KT) * 64 + skk, \
             &lds[BUF][R][S * 4096 + wb8])

    const int NK = K >> 6;

    f32x4 acc[4][4];
#pragma unroll
    for (int f = 0; f < 4; ++f)
#pragma unroll
        for (int nf = 0; nf < 4; ++nf) acc[f][nf] = f32x4{0.f, 0.f, 0.f, 0.f};

    // prologue: S(0) full (6), S(1) B (4); wait vmcnt(4)
    GISSUE(0, 0, 0, 0, rbA); GISSUE(0, 0, 1, 0, rbA);
    GISSUE(0, 1, 0, 0, rb2); GISSUE(0, 1, 1, 0, rb2);
    GISSUE(0, 2, 0, 0, rb3); GISSUE(0, 2, 1, 0, rb3);
    if (NK > 1) {
        GISSUE(1, 1, 0, 1, rb2); GISSUE(1, 1, 1, 1, rb2);
        GISSUE(1, 2, 0, 1, rb3); GISSUE(1, 2, 1, 1, rb3);
        asm volatile("s_waitcnt vmcnt(4)" ::: "memory");
    } else {
        asm volatile("s_waitcnt vmcnt(0)" ::: "memory");
    }
    __builtin_amdgcn_s_barrier();

    for (int kt = 0; kt < NK; ++kt) {
        const int cur = kt & 1, nxt = cur ^ 1;
        const F16* Areg = &lds[cur][0][0];
        const F16* Breg = &lds[cur][1 + (wn >> 1)][0];
        f16x8 b[4][2];
#pragma unroll
        for (int nf = 0; nf < 4; ++nf)
#pragma unroll
            for (int ks = 0; ks < 2; ++ks)
                b[nf][ks] = *reinterpret_cast<const f16x8*>(
                    Breg + ((((wn & 1) * 4 + nf) * 2 + ks) * 64 + l) * 8);
#pragma unroll
        for (int p = 0; p < 2; ++p) {
            f16x8 a[2][2];
#pragma unroll
            for (int mf = 0; mf < 2; ++mf)
#pragma unroll
                for (int ks = 0; ks < 2; ++ks)
                    a[mf][ks] = *reinterpret_cast<const f16x8*>(
                        Areg + (((wm * 4 + 2 * p + mf) * 2 + ks) * 64 + l) * 8);
            if (p == 0) {
                if (kt + 1 < NK) { GISSUE(nxt, 0, 0, kt + 1, rbA); GISSUE(nxt, 0, 1, kt + 1, rbA); }
            } else {
                if (kt + 2 < NK) {
                    GISSUE(cur, 1, 0, kt + 2, rb2); GISSUE(cur, 1, 1, kt + 2, rb2);
                    GISSUE(cur, 2, 0, kt + 2, rb3); GISSUE(cur, 2, 1, kt + 2, rb3);
                }
            }
            __builtin_amdgcn_sched_barrier(0);
            __builtin_amdgcn_s_barrier();
            asm volatile("s_waitcnt lgkmcnt(0)" ::: "memory");
            __builtin_amdgcn_sched_barrier(0);
            __builtin_amdgcn_s_setprio(1);
#pragma unroll
            for (int mf = 0; mf < 2; ++mf)
#pragma unroll
                for (int nf = 0; nf < 4; ++nf)
#pragma unroll
                    for (int ks = 0; ks < 2; ++ks)
                        acc[2 * p + mf][nf] = __builtin_amdgcn_mfma_f32_16x16x32_f16(
                            a[mf][ks], b[nf][ks], acc[2 * p + mf][nf], 0, 0, 0);
            __builtin_amdgcn_s_setprio(0);
            __builtin_amdgcn_sched_barrier(0);
            if (p == 1) {
                if (kt + 2 < NK) asm volatile("s_waitcnt vmcnt(4)" ::: "memory");
                else             asm volatile("s_waitcnt vmcnt(0)" ::: "memory");
            }
            __builtin_amdgcn_s_barrier();
        }
    }
#undef GISSUE

    // epilogue: f32 out + bias
    const int col0 = (int)bcol + wn * 64;
    const int row0 = (int)brow + wm * 64;
#pragma unroll
    for (int nf = 0; nf < 4; ++nf) {
        const int gcol = col0 + nf * 16 + lr;
        const float bv = bias[gcol];
#pragma unroll
        for (int f = 0; f < 4; ++f)
#pragma unroll
            for (int r = 0; r < 4; ++r)
                fout[(long)(row0 + f * 16 + lg * 4 + r) * N + gcol] = acc[f][nf][r] + bv;
    }
}

// ---------------- flash attention (unchanged from round 4) ----------------
__global__ __launch_bounds__(256, 2) void attn_kernel(
    const F16* __restrict__ q_ws, const F16* __restrict__ k_ws,
    const F16* __restrict__ v_ws, F16* __restrict__ ctx)
{
    __shared__ __align__(16) F16 kt[2][64 * 128];
    __shared__ __align__(16) F16 vt[2][128 * 64];
    __shared__ __align__(16) F16 p_lds[4][2048];
    const int tid = threadIdx.x;
    const int w = tid >> 6, l = tid & 63;
    const int lr = l & 15, lg = l >> 4;
    const int work = (blockIdx.x & 7) * 64 + (blockIdx.x >> 3);
    const int bh = work >> 3, qt = work & 7;
    const int b = bh >> 4, h = bh & 15;
    const int q0 = qt * 128 + w * 32;

    const F16* kbh = k_ws + (long)bh * 1024 * 128;
    const F16* vbh = v_ws + (long)bh * 128 * 1024;

    f16x8 qf[2][4];
#pragma unroll
    for (int mi = 0; mi < 2; ++mi)
#pragma unroll
        for (int ks = 0; ks < 4; ++ks)
            qf[mi][ks] = *reinterpret_cast<const f16x8*>(
                q_ws + ((long)bh * 1024 + q0 + mi * 16 + lr) * 128 + ks * 32 + lg * 8);

    auto stage = [&](int buf, int kv0) {
#pragma unroll
        for (int t = 0; t < 4; ++t) {
            const int chunk = t * 256 + tid;
            const int row = chunk >> 4;
            const int colb = (chunk & 15) << 4;
            const int gcol = colb ^ ((row & 7) << 4);
            gl_lds16(kbh + (long)(kv0 + row) * 128 + (gcol >> 1),
                     &kt[buf][(t * 256 + w * 64) * 8]);
        }
#pragma unroll
        for (int t = 0; t < 4; ++t) {
            const int chunk = t * 256 + tid;
            const int d = chunk >> 3;
            const int colb = (chunk & 7) << 4;
            const int gcol = colb ^ ((d & 7) << 4);
            gl_lds16(vbh + (long)d * 1024 + kv0 + (gcol >> 1),
                     &vt[buf][(t * 256 + w * 64) * 8]);
        }
    };

    float mrun[2][4], lsum[2][4];
#pragma unroll
    for (int mi = 0; mi < 2; ++mi)
#pragma unroll
        for (int r = 0; r < 4; ++r) { mrun[mi][r] = -1e30f; lsum[mi][r] = 0.f; }
    f32x4 acc[2][8];
#pragma unroll
    for (int mi = 0; mi < 2; ++mi)
#pragma unroll
        for (int nf = 0; nf < 8; ++nf) acc[mi][nf] = f32x4{0.f, 0.f, 0.f, 0.f};

    stage(0, 0);
    __syncthreads();
    int cur = 0;
    for (int it = 0; it < 16; ++it) {
        if (it + 1 < 16) stage(cur ^ 1, (it + 1) * 64);

        f32x4 sc[2][4];
#pragma unroll
        for (int mi = 0; mi < 2; ++mi)
#pragma unroll
            for (int cf = 0; cf < 4; ++cf) sc[mi][cf] = f32x4{0.f, 0.f, 0.f, 0.f};
#pragma unroll
        for (int cf = 0; cf < 4; ++cf) {
#pragma unroll
            for (int ks = 0; ks < 4; ++ks) {
                const int row = cf * 16 + lr;
                const int eff = (ks * 64 + lg * 16) ^ ((row & 7) << 4);
                f16x8 kf = *reinterpret_cast<const f16x8*>(&kt[cur][row * 128 + (eff >> 1)]);
#pragma unroll
                for (int mi = 0; mi < 2; ++mi)
                    sc[mi][cf] = __builtin_amdgcn_mfma_f32_16x16x32_f16(qf[mi][ks], kf, sc[mi][cf], 0, 0, 0);
            }
        }

#pragma unroll
        for (int mi = 0; mi < 2; ++mi) {
            float t4[4];
#pragma unroll
            for (int r = 0; r < 4; ++r)
                t4[r] = fmaxf(fmaxf(sc[mi][0][r], sc[mi][1][r]), fmaxf(sc[mi][2][r], sc[mi][3][r]));
#pragma unroll
            for (int msk = 1; msk < 16; msk <<= 1)
#pragma unroll
                for (int r = 0; r < 4; ++r) t4[r] = fmaxf(t4[r], __shfl_xor(t4[r], msk));
            float al[4], rs[4], p[4][4];
#pragma unroll
            for (int r = 0; r < 4; ++r) {
                const float mn = fmaxf(mrun[mi][r], t4[r]);
                al[r] = __expf(mrun[mi][r] - mn);
                mrun[mi][r] = mn;
#pragma unroll
                for (int cf = 0; cf < 4; ++cf) p[cf][r] = __expf(sc[mi][cf][r] - mn);
                rs[r] = (p[0][r] + p[1][r]) + (p[2][r] + p[3][r]);
            }
#pragma unroll
            for (int msk = 1; msk < 16; msk <<= 1)
#pragma unroll
                for (int r = 0; r < 4; ++r) rs[r] += __shfl_xor(rs[r], msk);
#pragma unroll
            for (int r = 0; r < 4; ++r) lsum[mi][r] = lsum[mi][r] * al[r] + rs[r];
#pragma unroll
            for (int nf = 0; nf < 8; ++nf)
#pragma unroll
                for (int r = 0; r < 4; ++r) acc[mi][nf][r] *= al[r];
#pragma unroll
            for (int cf = 0; cf < 4; ++cf)
#pragma unroll
                for (int r = 0; r < 4; ++r) {
                    const int chunk = (mi * 2 + (cf >> 1)) * 64 + (lg * 4 + r) + ((cf & 1) * 2 + (lr >> 3)) * 16;
                    p_lds[w][chunk * 8 + (lr & 7)] = (F16)p[cf][r];
                }
        }

        f16x8 pf[2][2];
#pragma unroll
        for (int mi = 0; mi < 2; ++mi)
#pragma unroll
            for (int half = 0; half < 2; ++half)
                pf[mi][half] = *reinterpret_cast<const f16x8*>(&p_lds[w][((mi * 2 + half) * 64 + l) * 8]);
#pragma unroll
        for (int nf = 0; nf < 8; ++nf) {
#pragma unroll
            for (int half = 0; half < 2; ++half) {
                const int d = nf * 16 + lr;
                const int eff = (half * 64 + lg * 16) ^ ((d & 7) << 4);
                f16x8 vf = *reinterpret_cast<const f16x8*>(&vt[cur][d * 64 + (eff >> 1)]);
#pragma unroll
                for (int mi = 0; mi < 2; ++mi)
                    acc[mi][nf] = __builtin_amdgcn_mfma_f32_16x16x32_f16(pf[mi][half], vf, acc[mi][nf], 0, 0, 0);
            }
        }
        __syncthreads();
        cur ^= 1;
    }

#pragma unroll
    for (int mi = 0; mi < 2; ++mi) {
        float inv[4];
#pragma unroll
        for (int r = 0; r < 4; ++r) inv[r] = 1.f / lsum[mi][r];
#pragma unroll
        for (int nf = 0; nf < 8; ++nf)
#pragma unroll
            for (int r = 0; r < 4; ++r) {
                const int s = q0 + mi * 16 + lg * 4 + r;
                const int e = h * 128 + nf * 16 + lr;
                ctx[((long)(b * 1024 + s)) * 2048 + e] = (F16)(acc[mi][nf][r] * inv[r]);
            }
    }
}

// ---------------- launch ----------------
extern "C" void kernel_launch(void* const* d_in, const int* in_sizes, int n_in,
                              void* d_out, int out_size, void* d_ws, size_t ws_size,
                              hipStream_t stream) {
    const float* query = (const float*)d_in[0];
    const float* w_in  = (const float*)d_in[1];
    const float* b_in  = (const float*)d_in[2];
    const float* w_out = (const float*)d_in[3];
    const float* b_out = (const float*)d_in[4];
    float* out = (float*)d_out;

    char* ws = (char*)d_ws;
    size_t off = 0;
    auto carve = [&](size_t bytes) -> void* {
        void* p = ws + off;
        off += (bytes + 255) & ~(size_t)255;
        return p;
    };
    F16* xq  = (F16*)carve(8388608ULL * 2);   // query f16 [4096][2048]
    F16* wih = (F16*)carve(12582912ULL * 2);  // in_proj_weight f16 [6144][2048]
    F16* woh = (F16*)carve(4194304ULL * 2);   // out_proj_weight f16 [2048][2048]
    F16* qws = (F16*)carve(8388608ULL * 2);   // Q [B,H,S,D] pre-scaled
    F16* kws = (F16*)carve(8388608ULL * 2);   // K [B,H,S,D]
    F16* vws = (F16*)carve(8388608ULL * 2);   // V [B,H,D,S] (transposed)
    F16* ctx = (F16*)carve(8388608ULL * 2);   // ctx [B,S,E]

    cvt_f32_f16<<<1024, 256, 0, stream>>>(query, xq, 8388608);
    cvt_f32_f16<<<1024, 256, 0, stream>>>(w_in, wih, 12582912);
    cvt_f32_f16<<<512, 256, 0, stream>>>(w_out, woh, 4194304);

    // QKV: M=4096, N=6144, K=2048 -> 384 blocks (16x24)
    gemm8qkv<<<384, 512, 0, stream>>>(xq, wih, b_in, qws, kws, vws, 4096, 6144, 2048);
    attn_kernel<<<512, 256, 0, stream>>>(qws, kws, vws, ctx);
    // out proj: M=4096, N=2048, K=2048 -> 256 blocks (32x8), 1/CU exactly
    gemm8out<<<256, 512, 0, stream>>>(ctx, woh, b_out, out, 4096, 2048, 2048);
}

// Round 9
// 394.016 us; speedup vs baseline: 1.5659x; 1.0222x over previous
//
#include <hip/hip_runtime.h>
#include <hip/hip_fp16.h>

#define F16 _Float16
typedef F16 f16x8 __attribute__((ext_vector_type(8)));
typedef F16 f16x4 __attribute__((ext_vector_type(4)));
typedef float f32x4 __attribute__((ext_vector_type(4)));

// ---------------- f32 -> f16 convert (vectorized) ----------------
__global__ void cvt_f32_f16(const float* __restrict__ src, F16* __restrict__ dst, int n) {
    int idx = blockIdx.x * blockDim.x + threadIdx.x;
    int stride = gridDim.x * blockDim.x;
    for (int i = idx * 4; i < n; i += stride * 4) {
        float4 v = *reinterpret_cast<const float4*>(src + i);
        f16x4 o;
        o[0] = (F16)v.x; o[1] = (F16)v.y; o[2] = (F16)v.z; o[3] = (F16)v.w;
        *reinterpret_cast<f16x4*>(dst + i) = o;
    }
}

// ---------------- async global->LDS 16B ----------------
__device__ __forceinline__ void gl_lds16(const F16* g, F16* l) {
    __builtin_amdgcn_global_load_lds(
        (const __attribute__((address_space(1))) void*)g,
        (__attribute__((address_space(3))) void*)l, 16, 0, 0);
}

// ---------------- QKV GEMM: 256x256 8-phase (T3+T4+T5) ----------------
// (unchanged from round 7: 152us, FETCH 86MB, MfmaUtil 27%)
__global__ __launch_bounds__(512, 2) void gemm8qkv(
    const F16* __restrict__ A, const F16* __restrict__ Bw, const float* __restrict__ bias,
    F16* __restrict__ q_ws, F16* __restrict__ k_ws, F16* __restrict__ v_ws,
    int M, int N, int K)
{
    __shared__ __align__(16) F16 lds[2][4][8192];  // 128 KiB
    const int tid = threadIdx.x;
    const int w = tid >> 6, l = tid & 63;
    const int lr = l & 15, lg = l >> 4;
    const int wm = w >> 2, wn = w & 3;

    const int xcd = (int)blockIdx.x & 7, s5 = (int)blockIdx.x >> 3;  // s5 0..47
    const int mb = (xcd & 1) * 8 + s5 / 6;
    const int nb = (xcd >> 1) * 6 + s5 % 6;
    const long brow = (long)mb * 256, bcol = (long)nb * 256;

    const F16* rb0 = A + brow * K;
    const F16* rb1 = rb0 + 128 * (long)K;
    const F16* rb2 = Bw + bcol * K;
    const F16* rb3 = rb2 + 128 * (long)K;

    const int sr0 = ((tid >> 7) << 4) + (tid & 15);
    const int skk = (((tid >> 6) & 1) << 5) + (((tid >> 4) & 3) << 3);
    const int wb8 = (w << 6) * 8;

#define GISSUE(BUF, R, S, KT, RB) \
    gl_lds16(RB + (long)(sr0 + S * 64) * K + (KT) * 64 + skk, \
             &lds[BUF][R][S * 4096 + wb8])

    const int NK = K >> 6;

    f32x4 acc[8][4];
#pragma unroll
    for (int f = 0; f < 8; ++f)
#pragma unroll
        for (int nf = 0; nf < 4; ++nf) acc[f][nf] = f32x4{0.f, 0.f, 0.f, 0.f};

    GISSUE(0, 0, 0, 0, rb0); GISSUE(0, 0, 1, 0, rb0);
    GISSUE(0, 1, 0, 0, rb1); GISSUE(0, 1, 1, 0, rb1);
    GISSUE(0, 2, 0, 0, rb2); GISSUE(0, 2, 1, 0, rb2);
    GISSUE(0, 3, 0, 0, rb3); GISSUE(0, 3, 1, 0, rb3);
    if (NK > 1) {
        GISSUE(1, 2, 0, 1, rb2); GISSUE(1, 2, 1, 1, rb2);
        GISSUE(1, 3, 0, 1, rb3); GISSUE(1, 3, 1, 1, rb3);
        GISSUE(1, 0, 0, 1, rb0); GISSUE(1, 1, 0, 1, rb1);
        asm volatile("s_waitcnt vmcnt(6)" ::: "memory");
    } else {
        asm volatile("s_waitcnt vmcnt(0)" ::: "memory");
    }
    __builtin_amdgcn_s_barrier();

    for (int kt = 0; kt < NK; ++kt) {
        const int cur = kt & 1, nxt = cur ^ 1;
        const F16* Areg = &lds[cur][wm][0];
        const F16* Breg = &lds[cur][2 + (wn >> 1)][0];
        f16x8 b[4][2];
#pragma unroll
        for (int nf = 0; nf < 4; ++nf)
#pragma unroll
            for (int ks = 0; ks < 2; ++ks)
                b[nf][ks] = *reinterpret_cast<const f16x8*>(
                    Breg + ((((wn & 1) * 4 + nf) * 2 + ks) * 64 + l) * 8);
#pragma unroll
        for (int p = 0; p < 4; ++p) {
            f16x8 a[2][2];
#pragma unroll
            for (int mf = 0; mf < 2; ++mf)
#pragma unroll
                for (int ks = 0; ks < 2; ++ks)
                    a[mf][ks] = *reinterpret_cast<const f16x8*>(
                        Areg + (((2 * p + mf) * 2 + ks) * 64 + l) * 8);
            if (p == 0) {
                if (kt + 1 < NK) { GISSUE(nxt, 0, 1, kt + 1, rb0); GISSUE(nxt, 1, 1, kt + 1, rb1); }
            } else if (p == 1) {
                if (kt + 2 < NK) { GISSUE(cur, 2, 0, kt + 2, rb2); GISSUE(cur, 2, 1, kt + 2, rb2); }
            } else if (p == 2) {
                if (kt + 2 < NK) { GISSUE(cur, 3, 0, kt + 2, rb3); GISSUE(cur, 3, 1, kt + 2, rb3); }
            } else {
                if (kt + 2 < NK) { GISSUE(cur, 0, 0, kt + 2, rb0); GISSUE(cur, 1, 0, kt + 2, rb1); }
            }
            __builtin_amdgcn_sched_barrier(0);
            __builtin_amdgcn_s_barrier();
            asm volatile("s_waitcnt lgkmcnt(0)" ::: "memory");
            __builtin_amdgcn_sched_barrier(0);
            __builtin_amdgcn_s_setprio(1);
#pragma unroll
            for (int mf = 0; mf < 2; ++mf)
#pragma unroll
                for (int nf = 0; nf < 4; ++nf)
#pragma unroll
                    for (int ks = 0; ks < 2; ++ks)
                        acc[2 * p + mf][nf] = __builtin_amdgcn_mfma_f32_16x16x32_f16(
                            a[mf][ks], b[nf][ks], acc[2 * p + mf][nf], 0, 0, 0);
            __builtin_amdgcn_s_setprio(0);
            __builtin_amdgcn_sched_barrier(0);
            if (p == 3) {
                if (kt + 2 < NK) asm volatile("s_waitcnt vmcnt(6)" ::: "memory");
                else             asm volatile("s_waitcnt vmcnt(0)" ::: "memory");
            }
            __builtin_amdgcn_s_barrier();
        }
    }
#undef GISSUE

    // epilogue: scatter q/k/v (C/D layout: row=lg*4+reg, col=lr)
    const int col0 = (int)bcol + wn * 64;
    const int row0 = (int)brow + wm * 128;
    const int part = (int)(bcol >> 11);
    const int bI = row0 >> 10;
    const int sb = row0 & 1023;
    const float scl = (part == 0) ? 0.08838834764831845f : 1.0f;  // 1/sqrt(128)
#pragma unroll
    for (int nf = 0; nf < 4; ++nf) {
        const int gcol = col0 + nf * 16 + lr;
        const float bv = bias[gcol];
        const int d = gcol & 127;
        const int hh = (gcol >> 7) & 15;
        if (part == 2) {
            F16* dst0 = v_ws + ((long)((bI * 16 + hh) * 128 + d)) * 1024;
#pragma unroll
            for (int f = 0; f < 8; ++f) {
                f16x4 pv;
#pragma unroll
                for (int r = 0; r < 4; ++r) pv[r] = (F16)(acc[f][nf][r] + bv);
                *reinterpret_cast<f16x4*>(dst0 + sb + f * 16 + lg * 4) = pv;
            }
        } else {
            F16* dst0 = ((part == 0) ? q_ws : k_ws) + ((long)(bI * 16 + hh) * 1024) * 128 + d;
#pragma unroll
            for (int f = 0; f < 8; ++f)
#pragma unroll
                for (int r = 0; r < 4; ++r)
                    dst0[(long)(sb + f * 16 + lg * 4 + r) * 128] =
                        (F16)((acc[f][nf][r] + bv) * scl);
        }
    }
}

// ---------------- out-proj GEMM: 128x256 tile, grid 256 = 1 block/CU ----------------
// (unchanged from round 7)
__global__ __launch_bounds__(512, 2) void gemm8out(
    const F16* __restrict__ A, const F16* __restrict__ Bw, const float* __restrict__ bias,
    float* __restrict__ fout, int M, int N, int K)
{
    __shared__ __align__(16) F16 lds[2][3][8192];  // 96 KiB
    const int tid = threadIdx.x;
    const int w = tid >> 6, l = tid & 63;
    const int lr = l & 15, lg = l >> 4;
    const int wm = w >> 2, wn = w & 3;

    const int xcd = (int)blockIdx.x & 7, s5 = (int)blockIdx.x >> 3;  // s5 0..31
    const int mb = (xcd & 3) * 8 + (s5 >> 2);
    const int nb = (xcd >> 2) * 4 + (s5 & 3);
    const long brow = (long)mb * 128, bcol = (long)nb * 256;

    const F16* rbA = A + brow * K;
    const F16* rb2 = Bw + bcol * K;
    const F16* rb3 = rb2 + 128 * (long)K;

    const int sr0 = ((tid >> 7) << 4) + (tid & 15);
    const int skk = (((tid >> 6) & 1) << 5) + (((tid >> 4) & 3) << 3);
    const int wb8 = (w << 6) * 8;

#define GISSUE(BUF, R, S, KT, RB) \
    gl_lds16(RB + (long)(sr0 + S * 64) * K + (KT) * 64 + skk, \
             &lds[BUF][R][S * 4096 + wb8])

    const int NK = K >> 6;

    f32x4 acc[4][4];
#pragma unroll
    for (int f = 0; f < 4; ++f)
#pragma unroll
        for (int nf = 0; nf < 4; ++nf) acc[f][nf] = f32x4{0.f, 0.f, 0.f, 0.f};

    GISSUE(0, 0, 0, 0, rbA); GISSUE(0, 0, 1, 0, rbA);
    GISSUE(0, 1, 0, 0, rb2); GISSUE(0, 1, 1, 0, rb2);
    GISSUE(0, 2, 0, 0, rb3); GISSUE(0, 2, 1, 0, rb3);
    if (NK > 1) {
        GISSUE(1, 1, 0, 1, rb2); GISSUE(1, 1, 1, 1, rb2);
        GISSUE(1, 2, 0, 1, rb3); GISSUE(1, 2, 1, 1, rb3);
        asm volatile("s_waitcnt vmcnt(4)" ::: "memory");
    } else {
        asm volatile("s_waitcnt vmcnt(0)" ::: "memory");
    }
    __builtin_amdgcn_s_barrier();

    for (int kt = 0; kt < NK; ++kt) {
        const int cur = kt & 1, nxt = cur ^ 1;
        const F16* Areg = &lds[cur][0][0];
        const F16* Breg = &lds[cur][1 + (wn >> 1)][0];
        f16x8 b[4][2];
#pragma unroll
        for (int nf = 0; nf < 4; ++nf)
#pragma unroll
            for (int ks = 0; ks < 2; ++ks)
                b[nf][ks] = *reinterpret_cast<const f16x8*>(
                    Breg + ((((wn & 1) * 4 + nf) * 2 + ks) * 64 + l) * 8);
#pragma unroll
        for (int p = 0; p < 2; ++p) {
            f16x8 a[2][2];
#pragma unroll
            for (int mf = 0; mf < 2; ++mf)
#pragma unroll
                for (int ks = 0; ks < 2; ++ks)
                    a[mf][ks] = *reinterpret_cast<const f16x8*>(
                        Areg + (((wm * 4 + 2 * p + mf) * 2 + ks) * 64 + l) * 8);
            if (p == 0) {
                if (kt + 1 < NK) { GISSUE(nxt, 0, 0, kt + 1, rbA); GISSUE(nxt, 0, 1, kt + 1, rbA); }
            } else {
                if (kt + 2 < NK) {
                    GISSUE(cur, 1, 0, kt + 2, rb2); GISSUE(cur, 1, 1, kt + 2, rb2);
                    GISSUE(cur, 2, 0, kt + 2, rb3); GISSUE(cur, 2, 1, kt + 2, rb3);
                }
            }
            __builtin_amdgcn_sched_barrier(0);
            __builtin_amdgcn_s_barrier();
            asm volatile("s_waitcnt lgkmcnt(0)" ::: "memory");
            __builtin_amdgcn_sched_barrier(0);
            __builtin_amdgcn_s_setprio(1);
#pragma unroll
            for (int mf = 0; mf < 2; ++mf)
#pragma unroll
                for (int nf = 0; nf < 4; ++nf)
#pragma unroll
                    for (int ks = 0; ks < 2; ++ks)
                        acc[2 * p + mf][nf] = __builtin_amdgcn_mfma_f32_16x16x32_f16(
                            a[mf][ks], b[nf][ks], acc[2 * p + mf][nf], 0, 0, 0);
            __builtin_amdgcn_s_setprio(0);
            __builtin_amdgcn_sched_barrier(0);
            if (p == 1) {
                if (kt + 2 < NK) asm volatile("s_waitcnt vmcnt(4)" ::: "memory");
                else             asm volatile("s_waitcnt vmcnt(0)" ::: "memory");
            }
            __builtin_amdgcn_s_barrier();
        }
    }
#undef GISSUE

    const int col0 = (int)bcol + wn * 64;
    const int row0 = (int)brow + wm * 64;
#pragma unroll
    for (int nf = 0; nf < 4; ++nf) {
        const int gcol = col0 + nf * 16 + lr;
        const float bv = bias[gcol];
#pragma unroll
        for (int f = 0; f < 4; ++f)
#pragma unroll
            for (int r = 0; r < 4; ++r)
                fout[(long)(row0 + f * 16 + lg * 4 + r) * N + gcol] = acc[f][nf][r] + bv;
    }
}

// ---------------- flash attention v3: swapped QK^T, lane-local softmax ----------------
// 512 blocks = 64 (b,h) * 8 q-tiles; 4 waves x 32 q-rows. LDS 80KB -> 2 blocks/CU.
// S^T = mfma(K,Q): lane owns q-col (l&15); 16 kv-scores in regs -> softmax is
// 15 in-lane ops + 2 shuffles (xor16/xor32). P^T via XOR-swizzled per-wave LDS
// (4x ds_write_b64 -> 2x ds_read_b128). PV: O^T = mfma(V^T, P^T); vf/qf/kf loads
// unchanged from v2. Defer-max (T13, THR=8). Epilogue: contiguous f16x4 stores.
__global__ __launch_bounds__(256, 2) void attn_kernel(
    const F16* __restrict__ q_ws, const F16* __restrict__ k_ws,
    const F16* __restrict__ v_ws, F16* __restrict__ ctx)
{
    __shared__ __align__(16) F16 kt[2][64 * 128];    // 32KB
    __shared__ __align__(16) F16 vt[2][128 * 64];    // 32KB
    __shared__ __align__(16) F16 plds[4][2][1024];   // 16KB: [wave][mi][16 q x 64 kv], XOR-swz
    const int tid = threadIdx.x;
    const int w = tid >> 6, l = tid & 63;
    const int lr = l & 15, lg = l >> 4;
    const int work = (blockIdx.x & 7) * 64 + (blockIdx.x >> 3);
    const int bh = work >> 3, qt = work & 7;
    const int b = bh >> 4, h = bh & 15;
    const int q0 = qt * 128 + w * 32;
    const int sw = (lr & 7) << 4;                    // per-q-row XOR swizzle (bytes)

    const F16* kbh = k_ws + (long)bh * 1024 * 128;
    const F16* vbh = v_ws + (long)bh * 128 * 1024;

    // Q frags (B-operand of swapped QK^T): lane = Q[q0+mi*16+lr][ks*32+lg*8..]
    f16x8 qf[2][4];
#pragma unroll
    for (int mi = 0; mi < 2; ++mi)
#pragma unroll
        for (int ks = 0; ks < 4; ++ks)
            qf[mi][ks] = *reinterpret_cast<const f16x8*>(
                q_ws + ((long)bh * 1024 + q0 + mi * 16 + lr) * 128 + ks * 32 + lg * 8);

    auto stage = [&](int buf, int kv0) {
#pragma unroll
        for (int t = 0; t < 4; ++t) {
            const int chunk = t * 256 + tid;
            const int row = chunk >> 4;
            const int colb = (chunk & 15) << 4;
            const int gcol = colb ^ ((row & 7) << 4);
            gl_lds16(kbh + (long)(kv0 + row) * 128 + (gcol >> 1),
                     &kt[buf][(t * 256 + w * 64) * 8]);
        }
#pragma unroll
        for (int t = 0; t < 4; ++t) {
            const int chunk = t * 256 + tid;
            const int d = chunk >> 3;
            const int colb = (chunk & 7) << 4;
            const int gcol = colb ^ ((d & 7) << 4);
            gl_lds16(vbh + (long)d * 1024 + kv0 + (gcol >> 1),
                     &vt[buf][(t * 256 + w * 64) * 8]);
        }
    };

    float mrun[2], lsum[2];
    mrun[0] = mrun[1] = -1e30f;
    lsum[0] = lsum[1] = 0.f;
    f32x4 acc[2][8];   // O^T: row d = nf*16+lg*4+r, col q = mi*16+lr
#pragma unroll
    for (int mi = 0; mi < 2; ++mi)
#pragma unroll
        for (int nf = 0; nf < 8; ++nf) acc[mi][nf] = f32x4{0.f, 0.f, 0.f, 0.f};

    stage(0, 0);
    __syncthreads();
    int cur = 0;
    for (int it = 0; it < 16; ++it) {
        if (it + 1 < 16) stage(cur ^ 1, (it + 1) * 64);

        // ---- QK^T swapped: S^T[kv = cf*16+lg*4+r][q = mi*16+lr] ----
        f32x4 sc[2][4];
#pragma unroll
        for (int mi = 0; mi < 2; ++mi)
#pragma unroll
            for (int cf = 0; cf < 4; ++cf) sc[mi][cf] = f32x4{0.f, 0.f, 0.f, 0.f};
#pragma unroll
        for (int cf = 0; cf < 4; ++cf) {
#pragma unroll
            for (int ks = 0; ks < 4; ++ks) {
                const int row = cf * 16 + lr;
                const int eff = (ks * 64 + lg * 16) ^ ((row & 7) << 4);
                f16x8 kf = *reinterpret_cast<const f16x8*>(&kt[cur][row * 128 + (eff >> 1)]);
#pragma unroll
                for (int mi = 0; mi < 2; ++mi)
                    sc[mi][cf] = __builtin_amdgcn_mfma_f32_16x16x32_f16(kf, qf[mi][ks], sc[mi][cf], 0, 0, 0);
            }
        }

        // ---- lane-local online softmax + P^T store ----
#pragma unroll
        for (int mi = 0; mi < 2; ++mi) {
            float nm = sc[mi][0][0];
#pragma unroll
            for (int cf = 0; cf < 4; ++cf)
#pragma unroll
                for (int r = 0; r < 4; ++r) nm = fmaxf(nm, sc[mi][cf][r]);
            nm = fmaxf(nm, __shfl_xor(nm, 16));
            nm = fmaxf(nm, __shfl_xor(nm, 32));
            const bool skip = __all(nm <= mrun[mi] + 8.0f);   // T13 defer-max
            float mn, al;
            if (skip) { mn = mrun[mi]; al = 1.0f; }
            else      { mn = fmaxf(mrun[mi], nm); al = __expf(mrun[mi] - mn); mrun[mi] = mn; }
            float rs = 0.f;
            char* prow = reinterpret_cast<char*>(&plds[w][mi][0]) + lr * 128;
#pragma unroll
            for (int cf = 0; cf < 4; ++cf) {
                f16x4 pv;
#pragma unroll
                for (int r = 0; r < 4; ++r) {
                    const float pe = __expf(sc[mi][cf][r] - mn);
                    rs += pe;
                    pv[r] = (F16)pe;
                }
                *reinterpret_cast<f16x4*>(prow + ((cf * 32 + lg * 8) ^ sw)) = pv;
            }
            rs += __shfl_xor(rs, 16);
            rs += __shfl_xor(rs, 32);
            lsum[mi] = lsum[mi] * al + rs;
            if (!skip) {
#pragma unroll
                for (int nf = 0; nf < 8; ++nf)
#pragma unroll
                    for (int r = 0; r < 4; ++r) acc[mi][nf][r] *= al;
            }
        }

        // ---- PV: O^T += V^T * P^T (vf as A, pf as B; compiler inserts lgkmcnt) ----
        f16x8 pf[2][2];
#pragma unroll
        for (int mi = 0; mi < 2; ++mi)
#pragma unroll
            for (int kvs = 0; kvs < 2; ++kvs)
                pf[mi][kvs] = *reinterpret_cast<const f16x8*>(
                    reinterpret_cast<char*>(&plds[w][mi][0]) + lr * 128 + ((kvs * 64 + lg * 16) ^ sw));
#pragma unroll
        for (int nf = 0; nf < 8; ++nf) {
#pragma unroll
            for (int kvs = 0; kvs < 2; ++kvs) {
                const int d = nf * 16 + lr;
                const int eff = (kvs * 64 + lg * 16) ^ ((d & 7) << 4);
                f16x8 vf = *reinterpret_cast<const f16x8*>(&vt[cur][d * 64 + (eff >> 1)]);
#pragma unroll
                for (int mi = 0; mi < 2; ++mi)
                    acc[mi][nf] = __builtin_amdgcn_mfma_f32_16x16x32_f16(vf, pf[mi][kvs], acc[mi][nf], 0, 0, 0);
            }
        }
        __syncthreads();
        cur ^= 1;
    }

    // ---- epilogue: O[q][d] = O^T[d][q]/lsum; 4 consecutive d per store ----
#pragma unroll
    for (int mi = 0; mi < 2; ++mi) {
        const float inv = 1.f / lsum[mi];
        const int s = q0 + mi * 16 + lr;
        F16* orow = ctx + ((long)(b * 1024 + s)) * 2048 + h * 128;
#pragma unroll
        for (int nf = 0; nf < 8; ++nf) {
            f16x4 ov;
#pragma unroll
            for (int r = 0; r < 4; ++r) ov[r] = (F16)(acc[mi][nf][r] * inv);
            *reinterpret_cast<f16x4*>(orow + nf * 16 + lg * 4) = ov;
        }
    }
}

// ---------------- launch ----------------
extern "C" void kernel_launch(void* const* d_in, const int* in_sizes, int n_in,
                              void* d_out, int out_size, void* d_ws, size_t ws_size,
                              hipStream_t stream) {
    const float* query = (const float*)d_in[0];
    const float* w_in  = (const float*)d_in[1];
    const float* b_in  = (const float*)d_in[2];
    const float* w_out = (const float*)d_in[3];
    const float* b_out = (const float*)d_in[4];
    float* out = (float*)d_out;

    char* ws = (char*)d_ws;
    size_t off = 0;
    auto carve = [&](size_t bytes) -> void* {
        void* p = ws + off;
        off += (bytes + 255) & ~(size_t)255;
        return p;
    };
    F16* xq  = (F16*)carve(8388608ULL * 2);   // query f16 [4096][2048]
    F16* wih = (F16*)carve(12582912ULL * 2);  // in_proj_weight f16 [6144][2048]
    F16* woh = (F16*)carve(4194304ULL * 2);   // out_proj_weight f16 [2048][2048]
    F16* qws = (F16*)carve(8388608ULL * 2);   // Q [B,H,S,D] pre-scaled
    F16* kws = (F16*)carve(8388608ULL * 2);   // K [B,H,S,D]
    F16* vws = (F16*)carve(8388608ULL * 2);   // V [B,H,D,S] (transposed)
    F16* ctx = (F16*)carve(8388608ULL * 2);   // ctx [B,S,E]

    cvt_f32_f16<<<1024, 256, 0, stream>>>(query, xq, 8388608);
    cvt_f32_f16<<<1024, 256, 0, stream>>>(w_in, wih, 12582912);
    cvt_f32_f16<<<512, 256, 0, stream>>>(w_out, woh, 4194304);

    gemm8qkv<<<384, 512, 0, stream>>>(xq, wih, b_in, qws, kws, vws, 4096, 6144, 2048);
    attn_kernel<<<512, 256, 0, stream>>>(qws, kws, vws, ctx);
    gemm8out<<<256, 512, 0, stream>>>(ctx, woh, b_out, out, 4096, 2048, 2048);
}